// Round 15
// baseline (367.126 us; speedup 1.0000x reference)
//
#include <hip/hip_runtime.h>
#include <hip/hip_bf16.h>
#include <math.h>
#include <stdint.h>

namespace {

constexpr int Bn  = 8;
constexpr int Nn  = 500;
constexpr int Qn  = 25;
constexpr int ENC = 512;
constexpr int DIN = 300;
constexpr int NCn = 70;
constexpr int NETn = 3;

typedef __attribute__((ext_vector_type(8))) short bf16x8_t;
typedef __attribute__((ext_vector_type(4))) float f32x4_t;

__device__ __forceinline__ unsigned short f2bf(float f) {
    union { __hip_bfloat16 b; unsigned short u; } r;
    r.b = __float2bfloat16(f);
    return r.u;
}
__device__ __forceinline__ bf16x8_t cvt8(float4 f0, float4 f1) {
    union { bf16x8_t v; __hip_bfloat162 b[4]; } r;
    r.b[0] = __float22bfloat162_rn(make_float2(f0.x, f0.y));
    r.b[1] = __float22bfloat162_rn(make_float2(f0.z, f0.w));
    r.b[2] = __float22bfloat162_rn(make_float2(f1.x, f1.y));
    r.b[3] = __float22bfloat162_rn(make_float2(f1.z, f1.w));
    return r.v;
}
__device__ __forceinline__ float bf2f(unsigned short h) {
    unsigned int u = ((unsigned int)h) << 16;
    return __builtin_bit_cast(float, u);
}
__device__ __forceinline__ float sigmoidf_(float x) { return 1.0f / (1.0f + expf(-x)); }

// ---------------------------------------------------------------------------
// Asum[b][i][j] = sum_e adj[b,e,i,j], fp32, j padded 500->512 with zeros.
__global__ __launch_bounds__(128) void sum_adj_pad_k(const float* __restrict__ adj,
                                                     float* __restrict__ Asum) {
    int bi = blockIdx.x;
    int b = bi / Nn, i = bi - b * Nn;
    int j = threadIdx.x * 4;
    float4 s = make_float4(0.f, 0.f, 0.f, 0.f);
    if (j < Nn) {
#pragma unroll
        for (int e = 0; e < NETn; ++e) {
            const float* p = adj + (((size_t)(b * NETn + e) * Nn) + i) * Nn + j;
            float4 v = *(const float4*)p;
            s.x += v.x; s.y += v.y; s.z += v.z; s.w += v.w;
        }
    }
    *(float4*)(Asum + ((size_t)bi) * 512 + j) = s;
}

// ---------------------------------------------------------------------------
// All weight transposes in one launch. z selects slice; idle blocks exit.
// sel2: Wh -> WhcT rows 0..511.  sel3: Wc rows 512..1023 -> WhcT rows 512..1023.
// sel4: Wc rows 0..511 -> WcHiT.
__global__ __launch_bounds__(256) void tcvt_all_k(
    const float* __restrict__ Wn, const float* __restrict__ Wq,
    const float* __restrict__ Wh, const float* __restrict__ Wc,
    const float* __restrict__ W1,
    unsigned short* __restrict__ WnT, unsigned short* __restrict__ WqT,
    unsigned short* __restrict__ WhcT, unsigned short* __restrict__ WcHiT,
    unsigned short* __restrict__ W1T) {
    __shared__ float tile[32][33];
    int sel = blockIdx.z;
    const float* in; unsigned short* out; int K, N, Kpad;
    if (sel == 0)      { in = Wn; out = WnT; K = DIN; N = ENC; Kpad = 320; }
    else if (sel == 1) { in = Wq; out = WqT; K = DIN; N = ENC; Kpad = 320; }
    else if (sel == 2) { in = Wh; out = WhcT; K = 512; N = ENC; Kpad = 512; }
    else if (sel == 3) { in = Wc + (size_t)512 * ENC; out = WhcT + (size_t)512 * 512;
                         K = 512; N = ENC; Kpad = 512; }
    else if (sel == 4) { in = Wc; out = WcHiT; K = 512; N = ENC; Kpad = 512; }
    else               { in = W1; out = W1T; K = 2048; N = 128; Kpad = 2048; }
    int n0 = blockIdx.x * 32, k0 = blockIdx.y * 32;
    if (n0 >= N || k0 >= Kpad) return;
    int tx = threadIdx.x & 31, ty = threadIdx.x >> 5;
#pragma unroll
    for (int r = 0; r < 4; ++r) {
        int k = k0 + ty * 4 + r;
        int n = n0 + tx;
        tile[ty * 4 + r][tx] = (k < K && n < N) ? in[(size_t)k * N + n] : 0.0f;
    }
    __syncthreads();
#pragma unroll
    for (int r = 0; r < 4; ++r) {
        int n = n0 + ty * 4 + r;
        int k = k0 + tx;
        if (n < N && k < Kpad) out[(size_t)n * Kpad + k] = f2bf(tile[tx][ty * 4 + r]);
    }
}

// ---------------------------------------------------------------------------
// MFMA core, BK=64, 64x64 tile (R13/R14-proven).
// AMODE 0: A fp32 (A2 concat, Klim clamp).  AMODE 1: A bf16 (Abf/Abf2 concat).
template <int AMODE>
__device__ __forceinline__ void mfma_core(
    const float* __restrict__ A, const float* __restrict__ A2,
    const unsigned short* __restrict__ Abf, const unsigned short* __restrict__ Abf2,
    int lda, int ksplit, int Klim,
    const unsigned short* __restrict__ Bt, int ldb,
    int m0, int n0, int K, int Mlim,
    unsigned short* As, unsigned short* Bts, f32x4_t acc[2][2]) {
    const int t = threadIdx.x;
    const int lane = t & 63;
    const int w = t >> 6;
    const int sm = t >> 2;
    const int sp = t & 3;
    const int sq = sp ^ ((sm >> 1) & 3);
    const int arow = m0 + sm;
    const bool rowok = arow < Mlim;
    const int wm = (w & 1) * 32, wn = (w >> 1) * 32;
    const int quad = lane >> 4, cidx = lane & 15;
    const int am0 = wm + cidx, am1 = wm + 16 + cidx;
    const int an0 = wn + cidx, an1 = wn + 16 + cidx;
    const int apo0 = am0 * 32 + (quad ^ ((am0 >> 1) & 3)) * 8;
    const int apo1 = am1 * 32 + (quad ^ ((am1 >> 1) & 3)) * 8;
    const int bpo0 = an0 * 32 + (quad ^ ((an0 >> 1) & 3)) * 8;
    const int bpo1 = an1 * 32 + (quad ^ ((an1 >> 1) & 3)) * 8;

    bf16x8_t ast0, ast1, bst0, bst1;
    auto stageA = [&](int kg) -> bf16x8_t {
        if (AMODE == 1) {
            bf16x8_t r = {0, 0, 0, 0, 0, 0, 0, 0};
            if (rowok) {
                const unsigned short* src =
                    (Abf2 != nullptr && kg >= ksplit)
                        ? Abf2 + (size_t)arow * lda + (kg - ksplit)
                        : Abf + (size_t)arow * lda + kg;
                r = *(const bf16x8_t*)src;
            }
            return r;
        } else {
            float4 f0 = make_float4(0.f, 0.f, 0.f, 0.f);
            float4 f1 = make_float4(0.f, 0.f, 0.f, 0.f);
            if (rowok) {
                const float* src = (A2 != nullptr && kg >= ksplit)
                                       ? A2 + (size_t)arow * lda + (kg - ksplit)
                                       : A + (size_t)arow * lda + kg;
                if (kg + 8 <= Klim) {
                    f0 = *(const float4*)src;
                    f1 = *(const float4*)(src + 4);
                } else if (kg + 4 <= Klim) {
                    f0 = *(const float4*)src;
                }
            }
            return cvt8(f0, f1);
        }
    };
    auto stage = [&](int k0) {
        int kg0 = k0 + sq * 8;
        int kg1 = k0 + 32 + sq * 8;
        ast0 = stageA(kg0);
        ast1 = stageA(kg1);
        const unsigned short* brow = Bt + (size_t)(n0 + sm) * ldb;
        bst0 = *(const bf16x8_t*)(brow + kg0);
        bst1 = *(const bf16x8_t*)(brow + kg1);
    };

    const int ktot = K >> 6;
    stage(0);
    *(bf16x8_t*)(As + t * 8) = ast0;
    *(bf16x8_t*)(As + 2048 + t * 8) = ast1;
    *(bf16x8_t*)(Bts + t * 8) = bst0;
    *(bf16x8_t*)(Bts + 2048 + t * 8) = bst1;
    for (int kt = 0; kt < ktot; ++kt) {
        __syncthreads();
        const int cur = (kt & 1) * 4096;
        const bool more = (kt + 1) < ktot;
        if (more) stage((kt + 1) << 6);
        {
            bf16x8_t a0 = *(const bf16x8_t*)(As + cur + apo0);
            bf16x8_t a1 = *(const bf16x8_t*)(As + cur + apo1);
            bf16x8_t b0 = *(const bf16x8_t*)(Bts + cur + bpo0);
            bf16x8_t b1 = *(const bf16x8_t*)(Bts + cur + bpo1);
            acc[0][0] = __builtin_amdgcn_mfma_f32_16x16x32_bf16(a0, b0, acc[0][0], 0, 0, 0);
            acc[0][1] = __builtin_amdgcn_mfma_f32_16x16x32_bf16(a0, b1, acc[0][1], 0, 0, 0);
            acc[1][0] = __builtin_amdgcn_mfma_f32_16x16x32_bf16(a1, b0, acc[1][0], 0, 0, 0);
            acc[1][1] = __builtin_amdgcn_mfma_f32_16x16x32_bf16(a1, b1, acc[1][1], 0, 0, 0);
        }
        {
            bf16x8_t a0 = *(const bf16x8_t*)(As + cur + 2048 + apo0);
            bf16x8_t a1 = *(const bf16x8_t*)(As + cur + 2048 + apo1);
            bf16x8_t b0 = *(const bf16x8_t*)(Bts + cur + 2048 + bpo0);
            bf16x8_t b1 = *(const bf16x8_t*)(Bts + cur + 2048 + bpo1);
            acc[0][0] = __builtin_amdgcn_mfma_f32_16x16x32_bf16(a0, b0, acc[0][0], 0, 0, 0);
            acc[0][1] = __builtin_amdgcn_mfma_f32_16x16x32_bf16(a0, b1, acc[0][1], 0, 0, 0);
            acc[1][0] = __builtin_amdgcn_mfma_f32_16x16x32_bf16(a1, b0, acc[1][0], 0, 0, 0);
            acc[1][1] = __builtin_amdgcn_mfma_f32_16x16x32_bf16(a1, b1, acc[1][1], 0, 0, 0);
        }
        if (more) {
            const int nxt = ((kt + 1) & 1) * 4096;
            *(bf16x8_t*)(As + nxt + t * 8) = ast0;
            *(bf16x8_t*)(As + nxt + 2048 + t * 8) = ast1;
            *(bf16x8_t*)(Bts + nxt + t * 8) = bst0;
            *(bf16x8_t*)(Bts + nxt + 2048 + t * 8) = bst1;
        }
    }
}

#define EPI_SETUP                                         \
    int t = threadIdx.x, lane = t & 63, w = t >> 6;       \
    int wm = (w & 1) * 32, wn = (w >> 1) * 32;            \
    int quad = lane >> 4, cidx = lane & 15;               \
    (void)wm; (void)wn; (void)quad; (void)cidx;

// ---------------------------------------------------------------------------
// nc = tanh(ng@Wn+bn) fp32;  lh0 = bf16(nc * rowmask)
__global__ __launch_bounds__(256) void gemm_nc_k(const float* __restrict__ ng,
                                                 const unsigned short* __restrict__ WnT,
                                                 const float* __restrict__ bn,
                                                 const int* __restrict__ lens,
                                                 float* __restrict__ nc,
                                                 unsigned short* __restrict__ lh0) {
    __shared__ __align__(16) unsigned short As[8192], Bts[8192];
    f32x4_t z = {0.f, 0.f, 0.f, 0.f};
    f32x4_t acc[2][2] = {{z, z}, {z, z}};
    int m0 = blockIdx.x * 64, n0 = blockIdx.y * 64;
    mfma_core<0>(ng, nullptr, nullptr, nullptr, DIN, 1 << 30, DIN, WnT, 320,
                 m0, n0, 320, Bn * Nn, As, Bts, acc);
    EPI_SETUP
#pragma unroll
    for (int nj = 0; nj < 2; ++nj) {
        int col = n0 + wn + nj * 16 + cidx;
        float bias = bn[col];
#pragma unroll
        for (int mi = 0; mi < 2; ++mi) {
#pragma unroll
            for (int r = 0; r < 4; ++r) {
                int row = m0 + wm + mi * 16 + quad * 4 + r;
                if (row < Bn * Nn) {
                    float tv = tanhf(acc[mi][nj][r] + bias);
                    int b = row / Nn, i = row - b * Nn;
                    float rm = (i < lens[b]) ? 1.0f : 0.0f;
                    nc[(size_t)row * ENC + col] = tv;
                    lh0[(size_t)row * ENC + col] = f2bf(tv * rm);
                }
            }
        }
    }
}

// ---------------------------------------------------------------------------
__global__ __launch_bounds__(256) void gemm_qc_k(const float* __restrict__ qg,
                                                 const unsigned short* __restrict__ WqT,
                                                 const float* __restrict__ bq,
                                                 float* __restrict__ qc) {
    __shared__ __align__(16) unsigned short As[8192], Bts[8192];
    f32x4_t z = {0.f, 0.f, 0.f, 0.f};
    f32x4_t acc[2][2] = {{z, z}, {z, z}};
    int m0 = blockIdx.x * 64, n0 = blockIdx.y * 64;
    mfma_core<0>(qg, nullptr, nullptr, nullptr, DIN, 1 << 30, DIN, WqT, 320,
                 m0, n0, 320, Bn * Qn, As, Bts, acc);
    EPI_SETUP
#pragma unroll
    for (int nj = 0; nj < 2; ++nj) {
        int col = n0 + wn + nj * 16 + cidx;
        float bias = bq[col];
#pragma unroll
        for (int mi = 0; mi < 2; ++mi) {
#pragma unroll
            for (int r = 0; r < 4; ++r) {
                int row = m0 + wm + mi * 16 + quad * 4 + r;
                if (row < Bn * Qn) qc[(size_t)row * ENC + col] = acc[mi][nj][r] + bias;
            }
        }
    }
}

// ---------------------------------------------------------------------------
// 128x64-tile MFMA core, BK=64, A bf16 only. 4 waves arranged 2(row)x2(col);
// each wave owns 64x32 (4x2 of 16x16). Per 64-k barrier: 16 MFMA, 12 ds_read.
// LDS: As 16384 shorts (2buf x 2half x 128x32), Bts 8192 shorts.
__device__ __forceinline__ void mfma_core128(
    const unsigned short* __restrict__ Abf, int lda,
    const unsigned short* __restrict__ Bt, int ldb,
    int m0, int n0, int K, int Mlim,
    unsigned short* As, unsigned short* Bts, f32x4_t acc[4][2]) {
    const int t = threadIdx.x;
    const int lane = t & 63;
    const int w = t >> 6;
    // A staging: row = t>>1 (0..127), two physical lines (t&1)*2 + {0,1}
    const int sra = t >> 1;
    const int spa = (t & 1) * 2;
    const int sqa0 = spa ^ ((sra >> 1) & 3);
    const int sqa1 = (spa + 1) ^ ((sra >> 1) & 3);
    const int arow = m0 + sra;
    const bool rowok = arow < Mlim;
    // B staging: threads 0..127, row = t>>1 (0..63), lines (t&1)*2 + {0,1}
    const bool bstager = t < 128;
    const int srb = t >> 1;
    const int sqb0 = sqa0;   // same formula (row>>1 identical)
    const int sqb1 = sqa1;
    // fragment read offsets
    const int wrow = (w & 1) * 64, wcol = (w >> 1) * 32;
    const int quad = lane >> 4, cidx = lane & 15;
    int apo[4], bpo[2];
#pragma unroll
    for (int i = 0; i < 4; ++i) {
        int am = wrow + i * 16 + cidx;
        apo[i] = am * 32 + (quad ^ ((am >> 1) & 3)) * 8;
    }
#pragma unroll
    for (int j = 0; j < 2; ++j) {
        int bn_ = wcol + j * 16 + cidx;
        bpo[j] = bn_ * 32 + (quad ^ ((bn_ >> 1) & 3)) * 8;
    }

    bf16x8_t a00, a01, a10, a11, b00, b01, b10, b11;
    auto stage = [&](int k0) {
        const unsigned short* arp = Abf + (size_t)arow * lda;
        bf16x8_t zr = {0, 0, 0, 0, 0, 0, 0, 0};
        a00 = rowok ? *(const bf16x8_t*)(arp + k0 + sqa0 * 8) : zr;
        a01 = rowok ? *(const bf16x8_t*)(arp + k0 + sqa1 * 8) : zr;
        a10 = rowok ? *(const bf16x8_t*)(arp + k0 + 32 + sqa0 * 8) : zr;
        a11 = rowok ? *(const bf16x8_t*)(arp + k0 + 32 + sqa1 * 8) : zr;
        if (bstager) {
            const unsigned short* brp = Bt + (size_t)(n0 + srb) * ldb;
            b00 = *(const bf16x8_t*)(brp + k0 + sqb0 * 8);
            b01 = *(const bf16x8_t*)(brp + k0 + sqb1 * 8);
            b10 = *(const bf16x8_t*)(brp + k0 + 32 + sqb0 * 8);
            b11 = *(const bf16x8_t*)(brp + k0 + 32 + sqb1 * 8);
        }
    };
    auto commit = [&](int buf) {
        unsigned short* ab = As + buf * 16384;
        *(bf16x8_t*)(ab + sra * 32 + spa * 8) = a00;
        *(bf16x8_t*)(ab + sra * 32 + (spa + 1) * 8) = a01;
        *(bf16x8_t*)(ab + 4096 + sra * 32 + spa * 8) = a10;
        *(bf16x8_t*)(ab + 4096 + sra * 32 + (spa + 1) * 8) = a11;
        if (bstager) {
            unsigned short* bb = Bts + buf * 8192;
            *(bf16x8_t*)(bb + srb * 32 + spa * 8) = b00;
            *(bf16x8_t*)(bb + srb * 32 + (spa + 1) * 8) = b01;
            *(bf16x8_t*)(bb + 2048 + srb * 32 + spa * 8) = b10;
            *(bf16x8_t*)(bb + 2048 + srb * 32 + (spa + 1) * 8) = b11;
        }
    };

    const int ktot = K >> 6;
    stage(0);
    commit(0);
    for (int kt = 0; kt < ktot; ++kt) {
        __syncthreads();
        const int buf = kt & 1;
        const unsigned short* ab = As + buf * 16384;
        const unsigned short* bb = Bts + buf * 8192;
        const bool more = (kt + 1) < ktot;
        if (more) stage((kt + 1) << 6);
#pragma unroll
        for (int h = 0; h < 2; ++h) {
            const unsigned short* ah = ab + h * 4096;
            const unsigned short* bh = bb + h * 2048;
            bf16x8_t bf0 = *(const bf16x8_t*)(bh + bpo[0]);
            bf16x8_t bf1 = *(const bf16x8_t*)(bh + bpo[1]);
#pragma unroll
            for (int i = 0; i < 4; ++i) {
                bf16x8_t af = *(const bf16x8_t*)(ah + apo[i]);
                acc[i][0] = __builtin_amdgcn_mfma_f32_16x16x32_bf16(af, bf0, acc[i][0], 0, 0, 0);
                acc[i][1] = __builtin_amdgcn_mfma_f32_16x16x32_bf16(af, bf1, acc[i][1], 0, 0, 0);
            }
        }
        if (more) commit((kt + 1) & 1);
    }
}

// ---------------------------------------------------------------------------
// Wide hop GEMM on 128x64 tiles: lh @ [Wh | Wc_lo]  (N=1024, K=512).
// cols 0..511 -> hm bf16; cols 512..1023 -> pa bf16 (partial att logits).
__global__ __launch_bounds__(256) void gemm_hmw_k(const unsigned short* __restrict__ lh,
                                                  const unsigned short* __restrict__ WhcT,
                                                  const float* __restrict__ bh,
                                                  const int* __restrict__ lens,
                                                  unsigned short* __restrict__ hm,
                                                  unsigned short* __restrict__ pa) {
    __shared__ __align__(16) unsigned short As[32768], Bts[16384];
    f32x4_t z = {0.f, 0.f, 0.f, 0.f};
    f32x4_t acc[4][2] = {{z, z}, {z, z}, {z, z}, {z, z}};
    int m0 = blockIdx.x * 128, n0 = blockIdx.y * 64;   // n0 in [0,1024)
    mfma_core128(lh, ENC, WhcT, 512, m0, n0, ENC, Bn * Nn, As, Bts, acc);
    int t = threadIdx.x, lane = t & 63, w = t >> 6;
    int wrow = (w & 1) * 64, wcol = (w >> 1) * 32;
    int quad = lane >> 4, cidx = lane & 15;
#pragma unroll
    for (int nj = 0; nj < 2; ++nj) {
        int col = n0 + wcol + nj * 16 + cidx;
        bool ishm = col < 512;
        float bias = ishm ? bh[col] : 0.0f;
#pragma unroll
        for (int mi = 0; mi < 4; ++mi) {
#pragma unroll
            for (int r = 0; r < 4; ++r) {
                int row = m0 + wrow + mi * 16 + quad * 4 + r;
                if (row < Bn * Nn) {
                    int b = row / Nn, i = row - b * Nn;
                    float rm = (i < lens[b]) ? 1.0f : 0.0f;
                    float v = acc[mi][nj][r];
                    if (ishm) {
                        hm[(size_t)row * ENC + col] = f2bf((v + bias) * rm);
                    } else {
                        pa[(size_t)row * ENC + (col - 512)] = f2bf(v);
                    }
                }
            }
        }
    }
}

// ---------------------------------------------------------------------------
// Sparse aggregation: upd[b,i,:] = hm[b,i,:] + sum_j Asum[b,i,j]*hm[b,j,:].
__global__ __launch_bounds__(256) void upd_sparse_k(const float* __restrict__ Asum,
                                                    const unsigned short* __restrict__ hm,
                                                    unsigned short* __restrict__ upd) {
    int wv = threadIdx.x >> 6, lane = threadIdx.x & 63;
    int row = blockIdx.x * 4 + wv;
    int b = row / Nn, i = row - b * Nn;
    const float* arow = Asum + (size_t)row * 512;
    const unsigned short* hmb = hm + (size_t)b * Nn * ENC;
    int d0 = lane * 8;

    float acc[8];
    {
        bf16x8_t h = *(const bf16x8_t*)(hmb + (size_t)i * ENC + d0);
#pragma unroll
        for (int j = 0; j < 8; ++j) acc[j] = bf2f((unsigned short)h[j]);
    }
#pragma unroll
    for (int c = 0; c < 8; ++c) {
        int j = c * 64 + lane;
        float val = (j < Nn) ? arow[j] : 0.0f;
        unsigned long long mask = __ballot(val != 0.0f);
        while (mask) {
            int b0 = __ffsll((unsigned long long)mask) - 1;
            mask &= mask - 1;
            int b1 = -1;
            if (mask) { b1 = __ffsll((unsigned long long)mask) - 1; mask &= mask - 1; }
            float v0 = __shfl(val, b0, 64);
            bf16x8_t x = *(const bf16x8_t*)(hmb + (size_t)(c * 64 + b0) * ENC + d0);
            float v1 = 0.0f;
            bf16x8_t y = {0, 0, 0, 0, 0, 0, 0, 0};
            if (b1 >= 0) {
                v1 = __shfl(val, b1, 64);
                y = *(const bf16x8_t*)(hmb + (size_t)(c * 64 + b1) * ENC + d0);
            }
#pragma unroll
            for (int k = 0; k < 8; ++k)
                acc[k] += v0 * bf2f((unsigned short)x[k]) + v1 * bf2f((unsigned short)y[k]);
        }
    }
    float4 o0 = make_float4(acc[0], acc[1], acc[2], acc[3]);
    float4 o1 = make_float4(acc[4], acc[5], acc[6], acc[7]);
    *(bf16x8_t*)(upd + (size_t)row * ENC + d0) = cvt8(o0, o1);
}

// ---------------------------------------------------------------------------
// att = sigmoid(upd@Wc_hi + pa + bc)*rm; lh_out = bf16(att*tanh(upd)+(1-att)*lh)
__global__ __launch_bounds__(256) void gemm_att_k(const unsigned short* __restrict__ upd,
                                                  const unsigned short* __restrict__ lh,
                                                  const unsigned short* __restrict__ WcHiT,
                                                  const unsigned short* __restrict__ pa,
                                                  const float* __restrict__ bc,
                                                  const int* __restrict__ lens,
                                                  unsigned short* __restrict__ lh_out) {
    __shared__ __align__(16) unsigned short As[8192], Bts[8192];
    f32x4_t z = {0.f, 0.f, 0.f, 0.f};
    f32x4_t acc[2][2] = {{z, z}, {z, z}};
    int m0 = blockIdx.x * 64, n0 = blockIdx.y * 64;
    mfma_core<1>(nullptr, nullptr, upd, nullptr, ENC, 1 << 30, ENC, WcHiT, 512,
                 m0, n0, ENC, Bn * Nn, As, Bts, acc);
    EPI_SETUP
#pragma unroll
    for (int nj = 0; nj < 2; ++nj) {
        int col = n0 + wn + nj * 16 + cidx;
        float bias = bc[col];
#pragma unroll
        for (int mi = 0; mi < 2; ++mi) {
#pragma unroll
            for (int r = 0; r < 4; ++r) {
                int row = m0 + wm + mi * 16 + quad * 4 + r;
                if (row < Bn * Nn) {
                    int b = row / Nn, i = row - b * Nn;
                    float rm = (i < lens[b]) ? 1.0f : 0.0f;
                    size_t off = (size_t)row * ENC + col;
                    float a = sigmoidf_(acc[mi][nj][r] + bf2f(pa[off]) + bias) * rm;
                    float u = bf2f(upd[off]);
                    float l = bf2f(lh[off]);
                    lh_out[off] = f2bf(a * tanhf(u) + (1.0f - a) * l);
                }
            }
        }
    }
}

// ---------------------------------------------------------------------------
// Materialize g = [nc | n2q | nc*n2q | nc*q2n] as bf16 [4000][2048].
__global__ __launch_bounds__(256) void gbf_k(const float* __restrict__ nc,
                                             const float* __restrict__ n2q,
                                             const float* __restrict__ q2n,
                                             unsigned short* __restrict__ gbf) {
    int row = blockIdx.x;
    int b = row / Nn;
    int t = threadIdx.x;
    int seg = t >> 6;
    int d = (t & 63) * 8;
    size_t off = (size_t)row * ENC + d;
    float4 a0, a1;
    if (seg == 0) {
        a0 = *(const float4*)(nc + off); a1 = *(const float4*)(nc + off + 4);
    } else if (seg == 1) {
        a0 = *(const float4*)(n2q + off); a1 = *(const float4*)(n2q + off + 4);
    } else if (seg == 2) {
        float4 x0 = *(const float4*)(nc + off), x1 = *(const float4*)(nc + off + 4);
        float4 y0 = *(const float4*)(n2q + off), y1 = *(const float4*)(n2q + off + 4);
        a0 = make_float4(x0.x * y0.x, x0.y * y0.y, x0.z * y0.z, x0.w * y0.w);
        a1 = make_float4(x1.x * y1.x, x1.y * y1.y, x1.z * y1.z, x1.w * y1.w);
    } else {
        float4 x0 = *(const float4*)(nc + off), x1 = *(const float4*)(nc + off + 4);
        const float* qp = q2n + (size_t)b * ENC + d;
        float4 y0 = *(const float4*)qp, y1 = *(const float4*)(qp + 4);
        a0 = make_float4(x0.x * y0.x, x0.y * y0.y, x0.z * y0.z, x0.w * y0.w);
        a1 = make_float4(x1.x * y1.x, x1.y * y1.y, x1.z * y1.z, x1.w * y1.w);
    }
    *(bf16x8_t*)(gbf + (size_t)row * 2048 + seg * 512 + d) = cvt8(a0, a1);
}

// ---------------------------------------------------------------------------
// g @ W1 split-K partials via MFMA; z = K-slice in [0,4) (512 wide).
__global__ __launch_bounds__(256) void gemm_final_k(const unsigned short* __restrict__ gbf,
                                                    const unsigned short* __restrict__ W1T,
                                                    float* __restrict__ part) {
    __shared__ __align__(16) unsigned short As[8192], Bts[8192];
    f32x4_t z4 = {0.f, 0.f, 0.f, 0.f};
    f32x4_t acc[2][2] = {{z4, z4}, {z4, z4}};
    int zz = blockIdx.z;
    int m0 = blockIdx.x * 64, n0 = blockIdx.y * 64;
    mfma_core<1>(nullptr, nullptr, gbf + zz * 512, nullptr, 2048, 1 << 30, 1 << 30,
                 W1T + zz * 512, 2048, m0, n0, 512, Bn * Nn, As, Bts, acc);
    EPI_SETUP
    constexpr int M = Bn * Nn;
#pragma unroll
    for (int nj = 0; nj < 2; ++nj) {
        int col = n0 + wn + nj * 16 + cidx;
#pragma unroll
        for (int mi = 0; mi < 2; ++mi) {
#pragma unroll
            for (int r = 0; r < 4; ++r) {
                int row = m0 + wm + mi * 16 + quad * 4 + r;
                if (row < M) part[((size_t)zz * M + row) * 128 + col] = acc[mi][nj][r];
            }
        }
    }
}

// ---------------------------------------------------------------------------
// Fused sim -> softmax(q) -> nodes2query + rowmax.  One wave per n-row.
__global__ __launch_bounds__(256) void sim_fused_k(const unsigned short* __restrict__ lh,
                                                   const float* __restrict__ qc,
                                                   const float* __restrict__ wa,
                                                   float* __restrict__ n2q,
                                                   float* __restrict__ rowmax) {
    __shared__ float qcs[Qn * ENC];
    __shared__ float qdot[32];
    int b = blockIdx.x;
    int t = threadIdx.x;
    const float* qcb = qc + (size_t)b * Qn * ENC;
    for (int i = t * 4; i < Qn * ENC; i += 1024) *(float4*)&qcs[i] = *(const float4*)&qcb[i];
    __syncthreads();
    {
        int q = t >> 3, j = t & 7;
        if (q < Qn) {
            float s = 0.f;
            for (int k = 0; k < 64; ++k) {
                int d = j + 8 * k;
                s += qcs[q * ENC + d] * wa[ENC + d];
            }
            s += __shfl_xor(s, 1, 64);
            s += __shfl_xor(s, 2, 64);
            s += __shfl_xor(s, 4, 64);
            if (j == 0) qdot[q] = s;
        }
    }
    __syncthreads();

    int wv = t >> 6, lane = t & 63;
    int n = blockIdx.y * 4 + wv;
    int dA = lane * 4;
    int dB = 256 + lane * 4;
    const unsigned short* lrow = lh + ((size_t)b * Nn + n) * ENC;
    ushort4 ua = *(const ushort4*)(lrow + dA);
    ushort4 ub = *(const ushort4*)(lrow + dB);
    float lv[8] = {bf2f(ua.x), bf2f(ua.y), bf2f(ua.z), bf2f(ua.w),
                   bf2f(ub.x), bf2f(ub.y), bf2f(ub.z), bf2f(ub.w)};
    float ndp = 0.f;
    float lvs[8];
#pragma unroll
    for (int j = 0; j < 4; ++j) {
        ndp += lv[j] * wa[dA + j];
        lvs[j] = lv[j] * wa[2 * ENC + dA + j];
        ndp += lv[4 + j] * wa[dB + j];
        lvs[4 + j] = lv[4 + j] * wa[2 * ENC + dB + j];
    }
#pragma unroll
    for (int off = 32; off; off >>= 1) ndp += __shfl_xor(ndp, off, 64);

    float s_[Qn];
#pragma unroll
    for (int q = 0; q < Qn; ++q) {
        float4 qa = *(const float4*)(qcs + q * ENC + dA);
        float4 qb = *(const float4*)(qcs + q * ENC + dB);
        s_[q] = lvs[0] * qa.x + lvs[1] * qa.y + lvs[2] * qa.z + lvs[3] * qa.w +
                lvs[4] * qb.x + lvs[5] * qb.y + lvs[6] * qb.z + lvs[7] * qb.w;
    }
#pragma unroll
    for (int q = 0; q < Qn; ++q) {
#pragma unroll
        for (int off = 32; off; off >>= 1) s_[q] += __shfl_xor(s_[q], off, 64);
    }
    float mx = -INFINITY;
#pragma unroll
    for (int q = 0; q < Qn; ++q) {
        s_[q] += ndp + qdot[q];
        mx = fmaxf(mx, s_[q]);
    }
    float sum = 0.f;
#pragma unroll
    for (int q = 0; q < Qn; ++q) { s_[q] = expf(s_[q] - mx); sum += s_[q]; }
    float inv = 1.0f / sum;
    float o[8] = {};
#pragma unroll
    for (int q = 0; q < Qn; ++q) {
        float4 qa = *(const float4*)(qcs + q * ENC + dA);
        float4 qb = *(const float4*)(qcs + q * ENC + dB);
        float p = s_[q] * inv;
        o[0] += p * qa.x; o[1] += p * qa.y; o[2] += p * qa.z; o[3] += p * qa.w;
        o[4] += p * qb.x; o[5] += p * qb.y; o[6] += p * qb.z; o[7] += p * qb.w;
    }
    float* orow = n2q + ((size_t)b * Nn + n) * ENC;
    *(float4*)(orow + dA) = make_float4(o[0], o[1], o[2], o[3]);
    *(float4*)(orow + dB) = make_float4(o[4], o[5], o[6], o[7]);
    if (lane == 0) rowmax[b * Nn + n] = mx;
}

// ---------------------------------------------------------------------------
// Fused bvec (softmax over rowmax) + q2n (bvec-weighted sum of nc).
__global__ __launch_bounds__(512) void bvec_q2n_k(const float* __restrict__ rowmax,
                                                  const float* __restrict__ nc,
                                                  float* __restrict__ q2n) {
    __shared__ float red[8];
    __shared__ float bvs[512];
    int b = blockIdx.x, t = threadIdx.x;
    float v = (t < Nn) ? rowmax[b * Nn + t] : -INFINITY;
    float m = v;
    for (int off = 32; off; off >>= 1) m = fmaxf(m, __shfl_xor(m, off, 64));
    if ((t & 63) == 0) red[t >> 6] = m;
    __syncthreads();
    float bm = red[0];
    for (int i = 1; i < 8; ++i) bm = fmaxf(bm, red[i]);
    float e = (t < Nn) ? expf(v - bm) : 0.0f;
    float ssum = e;
    for (int off = 32; off; off >>= 1) ssum += __shfl_xor(ssum, off, 64);
    __syncthreads();
    if ((t & 63) == 0) red[t >> 6] = ssum;
    __syncthreads();
    float tot = 0.f;
    for (int i = 0; i < 8; ++i) tot += red[i];
    bvs[t] = e / tot;
    __syncthreads();
    const float* ncb = nc + (size_t)b * Nn * ENC;
    float acc = 0.f;
    for (int n = 0; n < Nn; ++n) acc = fmaf(bvs[n], ncb[(size_t)n * ENC + t], acc);
    q2n[b * ENC + t] = acc;
}

// ---------------------------------------------------------------------------
// raw[row] = b2 + sum_h tanh(sum_z part[z][row][h] + b1[h]) * W2[h]
__global__ __launch_bounds__(256) void final_reduce_k(const float* __restrict__ part,
                                                      const float* __restrict__ b1p,
                                                      const float* __restrict__ W2p,
                                                      const float* __restrict__ b2p,
                                                      float* __restrict__ raw) {
    constexpr int M = Bn * Nn;
    int wave = threadIdx.x >> 6, lane = threadIdx.x & 63;
    int row = blockIdx.x * 4 + wave;
    if (row >= M) return;
    float v0 = 0.f, v1 = 0.f;
#pragma unroll
    for (int s = 0; s < 4; ++s) {
        const float* pr = part + ((size_t)s * M + row) * 128;
        v0 += pr[lane];
        v1 += pr[lane + 64];
    }
    float p = tanhf(v0 + b1p[lane]) * W2p[lane] + tanhf(v1 + b1p[lane + 64]) * W2p[lane + 64];
    for (int off = 32; off; off >>= 1) p += __shfl_xor(p, off, 64);
    if (lane == 0) raw[row] = p + b2p[0];
}

// ---------------------------------------------------------------------------
__global__ __launch_bounds__(256) void predmax_k(const int* __restrict__ mask,
                                                 const float* __restrict__ raw,
                                                 float* __restrict__ out) {
    int idx = blockIdx.x * 4 + (threadIdx.x >> 6);
    int lane = threadIdx.x & 63;
    if (idx >= Bn * NCn) return;
    int b = idx / NCn, c = idx - b * NCn;
    const int* mrow = mask + ((size_t)b * NCn + c) * Nn;
    const float* rrow = raw + (size_t)b * Nn;
    float mx = -INFINITY;
    for (int n = lane; n < Nn; n += 64) {
        float v = mrow[n] ? rrow[n] : 0.0f;
        if (v == 0.0f) v = -1.0e6f;
        mx = fmaxf(mx, v);
    }
    for (int off = 32; off; off >>= 1) mx = fmaxf(mx, __shfl_xor(mx, off, 64));
    if (lane == 0) out[idx] = mx;
}

}  // namespace

extern "C" void kernel_launch(void* const* d_in, const int* in_sizes, int n_in,
                              void* d_out, int out_size, void* d_ws, size_t ws_size,
                              hipStream_t stream) {
    const float* nodes_glove  = (const float*)d_in[0];
    const float* query_glove  = (const float*)d_in[1];
    const float* adj          = (const float*)d_in[2];
    const int*   nodes_length = (const int*)d_in[3];
    const int*   maskp        = (const int*)d_in[4];
    const float* Wn = (const float*)d_in[5];
    const float* bn = (const float*)d_in[6];
    const float* Wq = (const float*)d_in[7];
    const float* bq = (const float*)d_in[8];
    const float* Wh = (const float*)d_in[9];
    const float* bh = (const float*)d_in[10];
    const float* Wc = (const float*)d_in[11];
    const float* bc = (const float*)d_in[12];
    const float* wa = (const float*)d_in[13];
    const float* W1 = (const float*)d_in[14];
    const float* b1 = (const float*)d_in[15];
    const float* W2 = (const float*)d_in[16];
    const float* b2 = (const float*)d_in[17];
    float* out = (float*)d_out;

    float* ws = (float*)d_ws;
    size_t off = 0;
    auto alloc = [&](size_t n) { float* p = ws + off; off += n; return p; };
    constexpr size_t ME  = (size_t)Bn * Nn * ENC;       // 2,048,000 fp32 elems
    constexpr size_t MEH = ME / 2;
    float* nc   = alloc(ME);
    float* Asum = alloc(ME);       // fp32 adjacency; then n2q; then part buf
    unsigned short* pa  = (unsigned short*)alloc(MEH);  // bf16 partial att logits
    unsigned short* lh0 = (unsigned short*)alloc(MEH);
    unsigned short* lh1 = (unsigned short*)alloc(MEH);
    unsigned short* upd = (unsigned short*)alloc(MEH);
    unsigned short* hm  = (unsigned short*)alloc(MEH);
    unsigned short* gbf = (unsigned short*)alloc(ME * 2);   // [4000][2048] bf16
    float* qc   = alloc((size_t)Bn * Qn * ENC);
    float* rowmax = alloc(Bn * Nn);
    float* q2n    = alloc(Bn * ENC);
    float* raw    = alloc(Bn * Nn);
    unsigned short* WnT  = (unsigned short*)alloc((size_t)ENC * 320 / 2);
    unsigned short* WqT  = (unsigned short*)alloc((size_t)ENC * 320 / 2);
    unsigned short* WhcT = (unsigned short*)alloc((size_t)1024 * 512 / 2);
    unsigned short* WcHiT = (unsigned short*)alloc((size_t)512 * 512 / 2);
    unsigned short* W1T  = (unsigned short*)alloc((size_t)128 * 2048 / 2);
    alloc(16384);  // tail pad
    float* n2q  = Asum;            // phase 2
    float* part = Asum;            // phase 3 (after gbf consumed n2q)

    constexpr int M = Bn * Nn;  // 4000

    sum_adj_pad_k<<<dim3(Bn * Nn), 128, 0, stream>>>(adj, Asum);
    tcvt_all_k<<<dim3(16, 64, 6), 256, 0, stream>>>(Wn, Wq, Wh, Wc, W1,
                                                    WnT, WqT, WhcT, WcHiT, W1T);

    gemm_nc_k<<<dim3((M + 63) / 64, 8), 256, 0, stream>>>(nodes_glove, WnT, bn,
                                                          nodes_length, nc, lh0);
    gemm_qc_k<<<dim3((Bn * Qn + 63) / 64, 8), 256, 0, stream>>>(query_glove, WqT, bq, qc);

    // 3 hops; cur starts at lh0, after 3 swaps cur==lh1.
    unsigned short* cur = lh0;
    unsigned short* nxt = lh1;
    for (int h = 0; h < 3; ++h) {
        gemm_hmw_k<<<dim3((M + 127) / 128, 16), 256, 0, stream>>>(cur, WhcT, bh,
                                                                  nodes_length, hm, pa);
        upd_sparse_k<<<dim3(M / 4), 256, 0, stream>>>(Asum, hm, upd);
        gemm_att_k<<<dim3((M + 63) / 64, 8), 256, 0, stream>>>(upd, cur, WcHiT, pa,
                                                               bc, nodes_length, nxt);
        unsigned short* tmp = cur; cur = nxt; nxt = tmp;
    }
    // cur == lh1 == final last_hop.

    sim_fused_k<<<dim3(Bn, 125), 256, 0, stream>>>(cur, qc, wa, n2q, rowmax);
    bvec_q2n_k<<<dim3(Bn), 512, 0, stream>>>(rowmax, nc, q2n);
    gbf_k<<<dim3(M), 256, 0, stream>>>(nc, n2q, q2n, gbf);       // consumes n2q
    gemm_final_k<<<dim3((M + 63) / 64, 2, 4), 256, 0, stream>>>(gbf, W1T, part);
    final_reduce_k<<<dim3((M + 3) / 4), 256, 0, stream>>>(part, b1, W2, b2, raw);
    predmax_k<<<dim3((Bn * NCn + 3) / 4), 256, 0, stream>>>(maskp, raw, out);
}

// Round 16
// 338.726 us; speedup vs baseline: 1.0838x; 1.0838x over previous
//
#include <hip/hip_runtime.h>
#include <hip/hip_bf16.h>
#include <math.h>
#include <stdint.h>

namespace {

constexpr int Bn  = 8;
constexpr int Nn  = 500;
constexpr int Qn  = 25;
constexpr int ENC = 512;
constexpr int DIN = 300;
constexpr int NCn = 70;
constexpr int NETn = 3;

typedef __attribute__((ext_vector_type(8))) short bf16x8_t;
typedef __attribute__((ext_vector_type(4))) float f32x4_t;

__device__ __forceinline__ unsigned short f2bf(float f) {
    union { __hip_bfloat16 b; unsigned short u; } r;
    r.b = __float2bfloat16(f);
    return r.u;
}
__device__ __forceinline__ bf16x8_t cvt8(float4 f0, float4 f1) {
    union { bf16x8_t v; __hip_bfloat162 b[4]; } r;
    r.b[0] = __float22bfloat162_rn(make_float2(f0.x, f0.y));
    r.b[1] = __float22bfloat162_rn(make_float2(f0.z, f0.w));
    r.b[2] = __float22bfloat162_rn(make_float2(f1.x, f1.y));
    r.b[3] = __float22bfloat162_rn(make_float2(f1.z, f1.w));
    return r.v;
}
__device__ __forceinline__ float bf2f(unsigned short h) {
    unsigned int u = ((unsigned int)h) << 16;
    return __builtin_bit_cast(float, u);
}
__device__ __forceinline__ float sigmoidf_(float x) { return 1.0f / (1.0f + expf(-x)); }

// ---------------------------------------------------------------------------
// Asum[b][i][j] = sum_e adj[b,e,i,j], fp32, j padded 500->512 with zeros.
__global__ __launch_bounds__(128) void sum_adj_pad_k(const float* __restrict__ adj,
                                                     float* __restrict__ Asum) {
    int bi = blockIdx.x;
    int b = bi / Nn, i = bi - b * Nn;
    int j = threadIdx.x * 4;
    float4 s = make_float4(0.f, 0.f, 0.f, 0.f);
    if (j < Nn) {
#pragma unroll
        for (int e = 0; e < NETn; ++e) {
            const float* p = adj + (((size_t)(b * NETn + e) * Nn) + i) * Nn + j;
            float4 v = *(const float4*)p;
            s.x += v.x; s.y += v.y; s.z += v.z; s.w += v.w;
        }
    }
    *(float4*)(Asum + ((size_t)bi) * 512 + j) = s;
}

// ---------------------------------------------------------------------------
// All weight transposes in one launch. z selects slice; idle blocks exit.
// sel2: Wh -> WhcT rows 0..511.  sel3: Wc rows 512..1023 -> WhcT rows 512..1023
// (so WhcT = B^T for lh @ [Wh | Wc_lo]).  sel4: Wc rows 0..511 -> WcHiT.
__global__ __launch_bounds__(256) void tcvt_all_k(
    const float* __restrict__ Wn, const float* __restrict__ Wq,
    const float* __restrict__ Wh, const float* __restrict__ Wc,
    const float* __restrict__ W1,
    unsigned short* __restrict__ WnT, unsigned short* __restrict__ WqT,
    unsigned short* __restrict__ WhcT, unsigned short* __restrict__ WcHiT,
    unsigned short* __restrict__ W1T) {
    __shared__ float tile[32][33];
    int sel = blockIdx.z;
    const float* in; unsigned short* out; int K, N, Kpad;
    if (sel == 0)      { in = Wn; out = WnT; K = DIN; N = ENC; Kpad = 320; }
    else if (sel == 1) { in = Wq; out = WqT; K = DIN; N = ENC; Kpad = 320; }
    else if (sel == 2) { in = Wh; out = WhcT; K = 512; N = ENC; Kpad = 512; }
    else if (sel == 3) { in = Wc + (size_t)512 * ENC; out = WhcT + (size_t)512 * 512;
                         K = 512; N = ENC; Kpad = 512; }
    else if (sel == 4) { in = Wc; out = WcHiT; K = 512; N = ENC; Kpad = 512; }
    else               { in = W1; out = W1T; K = 2048; N = 128; Kpad = 2048; }
    int n0 = blockIdx.x * 32, k0 = blockIdx.y * 32;
    if (n0 >= N || k0 >= Kpad) return;
    int tx = threadIdx.x & 31, ty = threadIdx.x >> 5;
#pragma unroll
    for (int r = 0; r < 4; ++r) {
        int k = k0 + ty * 4 + r;
        int n = n0 + tx;
        tile[ty * 4 + r][tx] = (k < K && n < N) ? in[(size_t)k * N + n] : 0.0f;
    }
    __syncthreads();
#pragma unroll
    for (int r = 0; r < 4; ++r) {
        int n = n0 + ty * 4 + r;
        int k = k0 + tx;
        if (n < N && k < Kpad) out[(size_t)n * Kpad + k] = f2bf(tile[tx][ty * 4 + r]);
    }
}

// ---------------------------------------------------------------------------
// MFMA core, BK=64 (R13/R14-proven): 64x64 tile, 4 waves, double-buffered LDS,
// one barrier per 64-k step.  AMODE 0: A fp32 (A2 concat, Klim clamp).
// AMODE 1: A bf16 (Abf; optional Abf2 concat).  Bt: bf16 B^T [n][k].
// NOTE (R15 lesson): keep LDS at 32KB/block -> 4 blocks/CU. The 128x64-tile
// variant (96KB LDS, 1 block/CU) REGRESSED 340->367us despite better
// MFMA:ds_read ratio — blocks/CU dominates at these GEMM sizes.
template <int AMODE>
__device__ __forceinline__ void mfma_core(
    const float* __restrict__ A, const float* __restrict__ A2,
    const unsigned short* __restrict__ Abf, const unsigned short* __restrict__ Abf2,
    int lda, int ksplit, int Klim,
    const unsigned short* __restrict__ Bt, int ldb,
    int m0, int n0, int K, int Mlim,
    unsigned short* As, unsigned short* Bts, f32x4_t acc[2][2]) {
    const int t = threadIdx.x;
    const int lane = t & 63;
    const int w = t >> 6;
    const int sm = t >> 2;
    const int sp = t & 3;
    const int sq = sp ^ ((sm >> 1) & 3);
    const int arow = m0 + sm;
    const bool rowok = arow < Mlim;
    const int wm = (w & 1) * 32, wn = (w >> 1) * 32;
    const int quad = lane >> 4, cidx = lane & 15;
    const int am0 = wm + cidx, am1 = wm + 16 + cidx;
    const int an0 = wn + cidx, an1 = wn + 16 + cidx;
    const int apo0 = am0 * 32 + (quad ^ ((am0 >> 1) & 3)) * 8;
    const int apo1 = am1 * 32 + (quad ^ ((am1 >> 1) & 3)) * 8;
    const int bpo0 = an0 * 32 + (quad ^ ((an0 >> 1) & 3)) * 8;
    const int bpo1 = an1 * 32 + (quad ^ ((an1 >> 1) & 3)) * 8;

    bf16x8_t ast0, ast1, bst0, bst1;
    auto stageA = [&](int kg) -> bf16x8_t {
        if (AMODE == 1) {
            bf16x8_t r = {0, 0, 0, 0, 0, 0, 0, 0};
            if (rowok) {
                const unsigned short* src =
                    (Abf2 != nullptr && kg >= ksplit)
                        ? Abf2 + (size_t)arow * lda + (kg - ksplit)
                        : Abf + (size_t)arow * lda + kg;
                r = *(const bf16x8_t*)src;
            }
            return r;
        } else {
            float4 f0 = make_float4(0.f, 0.f, 0.f, 0.f);
            float4 f1 = make_float4(0.f, 0.f, 0.f, 0.f);
            if (rowok) {
                const float* src = (A2 != nullptr && kg >= ksplit)
                                       ? A2 + (size_t)arow * lda + (kg - ksplit)
                                       : A + (size_t)arow * lda + kg;
                if (kg + 8 <= Klim) {
                    f0 = *(const float4*)src;
                    f1 = *(const float4*)(src + 4);
                } else if (kg + 4 <= Klim) {
                    f0 = *(const float4*)src;
                }
            }
            return cvt8(f0, f1);
        }
    };
    auto stage = [&](int k0) {
        int kg0 = k0 + sq * 8;
        int kg1 = k0 + 32 + sq * 8;
        ast0 = stageA(kg0);
        ast1 = stageA(kg1);
        const unsigned short* brow = Bt + (size_t)(n0 + sm) * ldb;
        bst0 = *(const bf16x8_t*)(brow + kg0);
        bst1 = *(const bf16x8_t*)(brow + kg1);
    };

    const int ktot = K >> 6;
    stage(0);
    *(bf16x8_t*)(As + t * 8) = ast0;
    *(bf16x8_t*)(As + 2048 + t * 8) = ast1;
    *(bf16x8_t*)(Bts + t * 8) = bst0;
    *(bf16x8_t*)(Bts + 2048 + t * 8) = bst1;
    for (int kt = 0; kt < ktot; ++kt) {
        __syncthreads();
        const int cur = (kt & 1) * 4096;
        const bool more = (kt + 1) < ktot;
        if (more) stage((kt + 1) << 6);
        {
            bf16x8_t a0 = *(const bf16x8_t*)(As + cur + apo0);
            bf16x8_t a1 = *(const bf16x8_t*)(As + cur + apo1);
            bf16x8_t b0 = *(const bf16x8_t*)(Bts + cur + bpo0);
            bf16x8_t b1 = *(const bf16x8_t*)(Bts + cur + bpo1);
            acc[0][0] = __builtin_amdgcn_mfma_f32_16x16x32_bf16(a0, b0, acc[0][0], 0, 0, 0);
            acc[0][1] = __builtin_amdgcn_mfma_f32_16x16x32_bf16(a0, b1, acc[0][1], 0, 0, 0);
            acc[1][0] = __builtin_amdgcn_mfma_f32_16x16x32_bf16(a1, b0, acc[1][0], 0, 0, 0);
            acc[1][1] = __builtin_amdgcn_mfma_f32_16x16x32_bf16(a1, b1, acc[1][1], 0, 0, 0);
        }
        {
            bf16x8_t a0 = *(const bf16x8_t*)(As + cur + 2048 + apo0);
            bf16x8_t a1 = *(const bf16x8_t*)(As + cur + 2048 + apo1);
            bf16x8_t b0 = *(const bf16x8_t*)(Bts + cur + 2048 + bpo0);
            bf16x8_t b1 = *(const bf16x8_t*)(Bts + cur + 2048 + bpo1);
            acc[0][0] = __builtin_amdgcn_mfma_f32_16x16x32_bf16(a0, b0, acc[0][0], 0, 0, 0);
            acc[0][1] = __builtin_amdgcn_mfma_f32_16x16x32_bf16(a0, b1, acc[0][1], 0, 0, 0);
            acc[1][0] = __builtin_amdgcn_mfma_f32_16x16x32_bf16(a1, b0, acc[1][0], 0, 0, 0);
            acc[1][1] = __builtin_amdgcn_mfma_f32_16x16x32_bf16(a1, b1, acc[1][1], 0, 0, 0);
        }
        if (more) {
            const int nxt = ((kt + 1) & 1) * 4096;
            *(bf16x8_t*)(As + nxt + t * 8) = ast0;
            *(bf16x8_t*)(As + nxt + 2048 + t * 8) = ast1;
            *(bf16x8_t*)(Bts + nxt + t * 8) = bst0;
            *(bf16x8_t*)(Bts + nxt + 2048 + t * 8) = bst1;
        }
    }
}

#define EPI_SETUP                                         \
    int t = threadIdx.x, lane = t & 63, w = t >> 6;       \
    int wm = (w & 1) * 32, wn = (w >> 1) * 32;            \
    int quad = lane >> 4, cidx = lane & 15;               \
    (void)wm; (void)wn; (void)quad; (void)cidx;

// ---------------------------------------------------------------------------
// nc = tanh(ng@Wn+bn) fp32;  lh0 = bf16(nc * rowmask)
__global__ __launch_bounds__(256) void gemm_nc_k(const float* __restrict__ ng,
                                                 const unsigned short* __restrict__ WnT,
                                                 const float* __restrict__ bn,
                                                 const int* __restrict__ lens,
                                                 float* __restrict__ nc,
                                                 unsigned short* __restrict__ lh0) {
    __shared__ __align__(16) unsigned short As[8192], Bts[8192];
    f32x4_t z = {0.f, 0.f, 0.f, 0.f};
    f32x4_t acc[2][2] = {{z, z}, {z, z}};
    int m0 = blockIdx.x * 64, n0 = blockIdx.y * 64;
    mfma_core<0>(ng, nullptr, nullptr, nullptr, DIN, 1 << 30, DIN, WnT, 320,
                 m0, n0, 320, Bn * Nn, As, Bts, acc);
    EPI_SETUP
#pragma unroll
    for (int nj = 0; nj < 2; ++nj) {
        int col = n0 + wn + nj * 16 + cidx;
        float bias = bn[col];
#pragma unroll
        for (int mi = 0; mi < 2; ++mi) {
#pragma unroll
            for (int r = 0; r < 4; ++r) {
                int row = m0 + wm + mi * 16 + quad * 4 + r;
                if (row < Bn * Nn) {
                    float tv = tanhf(acc[mi][nj][r] + bias);
                    int b = row / Nn, i = row - b * Nn;
                    float rm = (i < lens[b]) ? 1.0f : 0.0f;
                    nc[(size_t)row * ENC + col] = tv;
                    lh0[(size_t)row * ENC + col] = f2bf(tv * rm);
                }
            }
        }
    }
}

// ---------------------------------------------------------------------------
__global__ __launch_bounds__(256) void gemm_qc_k(const float* __restrict__ qg,
                                                 const unsigned short* __restrict__ WqT,
                                                 const float* __restrict__ bq,
                                                 float* __restrict__ qc) {
    __shared__ __align__(16) unsigned short As[8192], Bts[8192];
    f32x4_t z = {0.f, 0.f, 0.f, 0.f};
    f32x4_t acc[2][2] = {{z, z}, {z, z}};
    int m0 = blockIdx.x * 64, n0 = blockIdx.y * 64;
    mfma_core<0>(qg, nullptr, nullptr, nullptr, DIN, 1 << 30, DIN, WqT, 320,
                 m0, n0, 320, Bn * Qn, As, Bts, acc);
    EPI_SETUP
#pragma unroll
    for (int nj = 0; nj < 2; ++nj) {
        int col = n0 + wn + nj * 16 + cidx;
        float bias = bq[col];
#pragma unroll
        for (int mi = 0; mi < 2; ++mi) {
#pragma unroll
            for (int r = 0; r < 4; ++r) {
                int row = m0 + wm + mi * 16 + quad * 4 + r;
                if (row < Bn * Qn) qc[(size_t)row * ENC + col] = acc[mi][nj][r] + bias;
            }
        }
    }
}

// ---------------------------------------------------------------------------
// Wide hop GEMM: lh @ [Wh | Wc_lo]  (N=1024, K=512).
// cols 0..511  -> hm = bf16((x + bh)*rm)
// cols 512..1023 -> pa = x  (fp32 partial att logits, lh @ Wc_lo)
__global__ __launch_bounds__(256) void gemm_hmw_k(const unsigned short* __restrict__ lh,
                                                  const unsigned short* __restrict__ WhcT,
                                                  const float* __restrict__ bh,
                                                  const int* __restrict__ lens,
                                                  unsigned short* __restrict__ hm,
                                                  float* __restrict__ pa) {
    __shared__ __align__(16) unsigned short As[8192], Bts[8192];
    f32x4_t z = {0.f, 0.f, 0.f, 0.f};
    f32x4_t acc[2][2] = {{z, z}, {z, z}};
    int m0 = blockIdx.x * 64, n0 = blockIdx.y * 64;   // n0 in [0,1024)
    mfma_core<1>(nullptr, nullptr, lh, nullptr, ENC, 1 << 30, ENC, WhcT, 512,
                 m0, n0, ENC, Bn * Nn, As, Bts, acc);
    EPI_SETUP
#pragma unroll
    for (int nj = 0; nj < 2; ++nj) {
        int col = n0 + wn + nj * 16 + cidx;
        bool ishm = col < 512;
        float bias = ishm ? bh[col] : 0.0f;
#pragma unroll
        for (int mi = 0; mi < 2; ++mi) {
#pragma unroll
            for (int r = 0; r < 4; ++r) {
                int row = m0 + wm + mi * 16 + quad * 4 + r;
                if (row < Bn * Nn) {
                    int b = row / Nn, i = row - b * Nn;
                    float rm = (i < lens[b]) ? 1.0f : 0.0f;
                    float v = acc[mi][nj][r];
                    if (ishm) {
                        hm[(size_t)row * ENC + col] = f2bf((v + bias) * rm);
                    } else {
                        pa[(size_t)row * ENC + (col - 512)] = v;
                    }
                }
            }
        }
    }
}

// ---------------------------------------------------------------------------
// Sparse aggregation: upd[b,i,:] = hm[b,i,:] + sum_j Asum[b,i,j]*hm[b,j,:].
__global__ __launch_bounds__(256) void upd_sparse_k(const float* __restrict__ Asum,
                                                    const unsigned short* __restrict__ hm,
                                                    unsigned short* __restrict__ upd) {
    int wv = threadIdx.x >> 6, lane = threadIdx.x & 63;
    int row = blockIdx.x * 4 + wv;
    int b = row / Nn, i = row - b * Nn;
    const float* arow = Asum + (size_t)row * 512;
    const unsigned short* hmb = hm + (size_t)b * Nn * ENC;
    int d0 = lane * 8;

    float acc[8];
    {
        bf16x8_t h = *(const bf16x8_t*)(hmb + (size_t)i * ENC + d0);
#pragma unroll
        for (int j = 0; j < 8; ++j) acc[j] = bf2f((unsigned short)h[j]);
    }
#pragma unroll
    for (int c = 0; c < 8; ++c) {
        int j = c * 64 + lane;
        float val = (j < Nn) ? arow[j] : 0.0f;
        unsigned long long mask = __ballot(val != 0.0f);
        while (mask) {
            int b0 = __ffsll((unsigned long long)mask) - 1;
            mask &= mask - 1;
            int b1 = -1;
            if (mask) { b1 = __ffsll((unsigned long long)mask) - 1; mask &= mask - 1; }
            float v0 = __shfl(val, b0, 64);
            bf16x8_t x = *(const bf16x8_t*)(hmb + (size_t)(c * 64 + b0) * ENC + d0);
            float v1 = 0.0f;
            bf16x8_t y = {0, 0, 0, 0, 0, 0, 0, 0};
            if (b1 >= 0) {
                v1 = __shfl(val, b1, 64);
                y = *(const bf16x8_t*)(hmb + (size_t)(c * 64 + b1) * ENC + d0);
            }
#pragma unroll
            for (int k = 0; k < 8; ++k)
                acc[k] += v0 * bf2f((unsigned short)x[k]) + v1 * bf2f((unsigned short)y[k]);
        }
    }
    float4 o0 = make_float4(acc[0], acc[1], acc[2], acc[3]);
    float4 o1 = make_float4(acc[4], acc[5], acc[6], acc[7]);
    *(bf16x8_t*)(upd + (size_t)row * ENC + d0) = cvt8(o0, o1);
}

// ---------------------------------------------------------------------------
// att = sigmoid(upd@Wc_hi + pa + bc)*rm; lh_out = bf16(att*tanh(upd)+(1-att)*lh)
// K = 512 only (the upd half) — pa carries the lh half.
__global__ __launch_bounds__(256) void gemm_att_k(const unsigned short* __restrict__ upd,
                                                  const unsigned short* __restrict__ lh,
                                                  const unsigned short* __restrict__ WcHiT,
                                                  const float* __restrict__ pa,
                                                  const float* __restrict__ bc,
                                                  const int* __restrict__ lens,
                                                  unsigned short* __restrict__ lh_out) {
    __shared__ __align__(16) unsigned short As[8192], Bts[8192];
    f32x4_t z = {0.f, 0.f, 0.f, 0.f};
    f32x4_t acc[2][2] = {{z, z}, {z, z}};
    int m0 = blockIdx.x * 64, n0 = blockIdx.y * 64;
    mfma_core<1>(nullptr, nullptr, upd, nullptr, ENC, 1 << 30, ENC, WcHiT, 512,
                 m0, n0, ENC, Bn * Nn, As, Bts, acc);
    EPI_SETUP
#pragma unroll
    for (int nj = 0; nj < 2; ++nj) {
        int col = n0 + wn + nj * 16 + cidx;
        float bias = bc[col];
#pragma unroll
        for (int mi = 0; mi < 2; ++mi) {
#pragma unroll
            for (int r = 0; r < 4; ++r) {
                int row = m0 + wm + mi * 16 + quad * 4 + r;
                if (row < Bn * Nn) {
                    int b = row / Nn, i = row - b * Nn;
                    float rm = (i < lens[b]) ? 1.0f : 0.0f;
                    size_t off = (size_t)row * ENC + col;
                    float a = sigmoidf_(acc[mi][nj][r] + pa[off] + bias) * rm;
                    float u = bf2f(upd[off]);
                    float l = bf2f(lh[off]);
                    lh_out[off] = f2bf(a * tanhf(u) + (1.0f - a) * l);
                }
            }
        }
    }
}

// ---------------------------------------------------------------------------
// Materialize g = [nc | n2q | nc*n2q | nc*q2n] as bf16 [4000][2048].
__global__ __launch_bounds__(256) void gbf_k(const float* __restrict__ nc,
                                             const float* __restrict__ n2q,
                                             const float* __restrict__ q2n,
                                             unsigned short* __restrict__ gbf) {
    int row = blockIdx.x;
    int b = row / Nn;
    int t = threadIdx.x;
    int seg = t >> 6;
    int d = (t & 63) * 8;
    size_t off = (size_t)row * ENC + d;
    float4 a0, a1;
    if (seg == 0) {
        a0 = *(const float4*)(nc + off); a1 = *(const float4*)(nc + off + 4);
    } else if (seg == 1) {
        a0 = *(const float4*)(n2q + off); a1 = *(const float4*)(n2q + off + 4);
    } else if (seg == 2) {
        float4 x0 = *(const float4*)(nc + off), x1 = *(const float4*)(nc + off + 4);
        float4 y0 = *(const float4*)(n2q + off), y1 = *(const float4*)(n2q + off + 4);
        a0 = make_float4(x0.x * y0.x, x0.y * y0.y, x0.z * y0.z, x0.w * y0.w);
        a1 = make_float4(x1.x * y1.x, x1.y * y1.y, x1.z * y1.z, x1.w * y1.w);
    } else {
        float4 x0 = *(const float4*)(nc + off), x1 = *(const float4*)(nc + off + 4);
        const float* qp = q2n + (size_t)b * ENC + d;
        float4 y0 = *(const float4*)qp, y1 = *(const float4*)(qp + 4);
        a0 = make_float4(x0.x * y0.x, x0.y * y0.y, x0.z * y0.z, x0.w * y0.w);
        a1 = make_float4(x1.x * y1.x, x1.y * y1.y, x1.z * y1.z, x1.w * y1.w);
    }
    *(bf16x8_t*)(gbf + (size_t)row * 2048 + seg * 512 + d) = cvt8(a0, a1);
}

// ---------------------------------------------------------------------------
// g @ W1 split-K partials via MFMA; z = K-slice in [0,4) (512 wide).
__global__ __launch_bounds__(256) void gemm_final_k(const unsigned short* __restrict__ gbf,
                                                    const unsigned short* __restrict__ W1T,
                                                    float* __restrict__ part) {
    __shared__ __align__(16) unsigned short As[8192], Bts[8192];
    f32x4_t z4 = {0.f, 0.f, 0.f, 0.f};
    f32x4_t acc[2][2] = {{z4, z4}, {z4, z4}};
    int zz = blockIdx.z;
    int m0 = blockIdx.x * 64, n0 = blockIdx.y * 64;
    mfma_core<1>(nullptr, nullptr, gbf + zz * 512, nullptr, 2048, 1 << 30, 1 << 30,
                 W1T + zz * 512, 2048, m0, n0, 512, Bn * Nn, As, Bts, acc);
    EPI_SETUP
    constexpr int M = Bn * Nn;
#pragma unroll
    for (int nj = 0; nj < 2; ++nj) {
        int col = n0 + wn + nj * 16 + cidx;
#pragma unroll
        for (int mi = 0; mi < 2; ++mi) {
#pragma unroll
            for (int r = 0; r < 4; ++r) {
                int row = m0 + wm + mi * 16 + quad * 4 + r;
                if (row < M) part[((size_t)zz * M + row) * 128 + col] = acc[mi][nj][r];
            }
        }
    }
}

// ---------------------------------------------------------------------------
// Fused sim -> softmax(q) -> nodes2query + rowmax.  One wave per n-row.
__global__ __launch_bounds__(256) void sim_fused_k(const unsigned short* __restrict__ lh,
                                                   const float* __restrict__ qc,
                                                   const float* __restrict__ wa,
                                                   float* __restrict__ n2q,
                                                   float* __restrict__ rowmax) {
    __shared__ float qcs[Qn * ENC];
    __shared__ float qdot[32];
    int b = blockIdx.x;
    int t = threadIdx.x;
    const float* qcb = qc + (size_t)b * Qn * ENC;
    for (int i = t * 4; i < Qn * ENC; i += 1024) *(float4*)&qcs[i] = *(const float4*)&qcb[i];
    __syncthreads();
    {
        int q = t >> 3, j = t & 7;
        if (q < Qn) {
            float s = 0.f;
            for (int k = 0; k < 64; ++k) {
                int d = j + 8 * k;
                s += qcs[q * ENC + d] * wa[ENC + d];
            }
            s += __shfl_xor(s, 1, 64);
            s += __shfl_xor(s, 2, 64);
            s += __shfl_xor(s, 4, 64);
            if (j == 0) qdot[q] = s;
        }
    }
    __syncthreads();

    int wv = t >> 6, lane = t & 63;
    int n = blockIdx.y * 4 + wv;
    int dA = lane * 4;
    int dB = 256 + lane * 4;
    const unsigned short* lrow = lh + ((size_t)b * Nn + n) * ENC;
    ushort4 ua = *(const ushort4*)(lrow + dA);
    ushort4 ub = *(const ushort4*)(lrow + dB);
    float lv[8] = {bf2f(ua.x), bf2f(ua.y), bf2f(ua.z), bf2f(ua.w),
                   bf2f(ub.x), bf2f(ub.y), bf2f(ub.z), bf2f(ub.w)};
    float ndp = 0.f;
    float lvs[8];
#pragma unroll
    for (int j = 0; j < 4; ++j) {
        ndp += lv[j] * wa[dA + j];
        lvs[j] = lv[j] * wa[2 * ENC + dA + j];
        ndp += lv[4 + j] * wa[dB + j];
        lvs[4 + j] = lv[4 + j] * wa[2 * ENC + dB + j];
    }
#pragma unroll
    for (int off = 32; off; off >>= 1) ndp += __shfl_xor(ndp, off, 64);

    float s_[Qn];
#pragma unroll
    for (int q = 0; q < Qn; ++q) {
        float4 qa = *(const float4*)(qcs + q * ENC + dA);
        float4 qb = *(const float4*)(qcs + q * ENC + dB);
        s_[q] = lvs[0] * qa.x + lvs[1] * qa.y + lvs[2] * qa.z + lvs[3] * qa.w +
                lvs[4] * qb.x + lvs[5] * qb.y + lvs[6] * qb.z + lvs[7] * qb.w;
    }
#pragma unroll
    for (int q = 0; q < Qn; ++q) {
#pragma unroll
        for (int off = 32; off; off >>= 1) s_[q] += __shfl_xor(s_[q], off, 64);
    }
    float mx = -INFINITY;
#pragma unroll
    for (int q = 0; q < Qn; ++q) {
        s_[q] += ndp + qdot[q];
        mx = fmaxf(mx, s_[q]);
    }
    float sum = 0.f;
#pragma unroll
    for (int q = 0; q < Qn; ++q) { s_[q] = expf(s_[q] - mx); sum += s_[q]; }
    float inv = 1.0f / sum;
    float o[8] = {};
#pragma unroll
    for (int q = 0; q < Qn; ++q) {
        float4 qa = *(const float4*)(qcs + q * ENC + dA);
        float4 qb = *(const float4*)(qcs + q * ENC + dB);
        float p = s_[q] * inv;
        o[0] += p * qa.x; o[1] += p * qa.y; o[2] += p * qa.z; o[3] += p * qa.w;
        o[4] += p * qb.x; o[5] += p * qb.y; o[6] += p * qb.z; o[7] += p * qb.w;
    }
    float* orow = n2q + ((size_t)b * Nn + n) * ENC;
    *(float4*)(orow + dA) = make_float4(o[0], o[1], o[2], o[3]);
    *(float4*)(orow + dB) = make_float4(o[4], o[5], o[6], o[7]);
    if (lane == 0) rowmax[b * Nn + n] = mx;
}

// ---------------------------------------------------------------------------
// Fused bvec (softmax over rowmax) + q2n (bvec-weighted sum of nc).
__global__ __launch_bounds__(512) void bvec_q2n_k(const float* __restrict__ rowmax,
                                                  const float* __restrict__ nc,
                                                  float* __restrict__ q2n) {
    __shared__ float red[8];
    __shared__ float bvs[512];
    int b = blockIdx.x, t = threadIdx.x;
    float v = (t < Nn) ? rowmax[b * Nn + t] : -INFINITY;
    float m = v;
    for (int off = 32; off; off >>= 1) m = fmaxf(m, __shfl_xor(m, off, 64));
    if ((t & 63) == 0) red[t >> 6] = m;
    __syncthreads();
    float bm = red[0];
    for (int i = 1; i < 8; ++i) bm = fmaxf(bm, red[i]);
    float e = (t < Nn) ? expf(v - bm) : 0.0f;
    float ssum = e;
    for (int off = 32; off; off >>= 1) ssum += __shfl_xor(ssum, off, 64);
    __syncthreads();
    if ((t & 63) == 0) red[t >> 6] = ssum;
    __syncthreads();
    float tot = 0.f;
    for (int i = 0; i < 8; ++i) tot += red[i];
    bvs[t] = e / tot;
    __syncthreads();
    const float* ncb = nc + (size_t)b * Nn * ENC;
    float acc = 0.f;
    for (int n = 0; n < Nn; ++n) acc = fmaf(bvs[n], ncb[(size_t)n * ENC + t], acc);
    q2n[b * ENC + t] = acc;
}

// ---------------------------------------------------------------------------
// raw[row] = b2 + sum_h tanh(sum_z part[z][row][h] + b1[h]) * W2[h]
__global__ __launch_bounds__(256) void final_reduce_k(const float* __restrict__ part,
                                                      const float* __restrict__ b1p,
                                                      const float* __restrict__ W2p,
                                                      const float* __restrict__ b2p,
                                                      float* __restrict__ raw) {
    constexpr int M = Bn * Nn;
    int wave = threadIdx.x >> 6, lane = threadIdx.x & 63;
    int row = blockIdx.x * 4 + wave;
    if (row >= M) return;
    float v0 = 0.f, v1 = 0.f;
#pragma unroll
    for (int s = 0; s < 4; ++s) {
        const float* pr = part + ((size_t)s * M + row) * 128;
        v0 += pr[lane];
        v1 += pr[lane + 64];
    }
    float p = tanhf(v0 + b1p[lane]) * W2p[lane] + tanhf(v1 + b1p[lane + 64]) * W2p[lane + 64];
    for (int off = 32; off; off >>= 1) p += __shfl_xor(p, off, 64);
    if (lane == 0) raw[row] = p + b2p[0];
}

// ---------------------------------------------------------------------------
__global__ __launch_bounds__(256) void predmax_k(const int* __restrict__ mask,
                                                 const float* __restrict__ raw,
                                                 float* __restrict__ out) {
    int idx = blockIdx.x * 4 + (threadIdx.x >> 6);
    int lane = threadIdx.x & 63;
    if (idx >= Bn * NCn) return;
    int b = idx / NCn, c = idx - b * NCn;
    const int* mrow = mask + ((size_t)b * NCn + c) * Nn;
    const float* rrow = raw + (size_t)b * Nn;
    float mx = -INFINITY;
    for (int n = lane; n < Nn; n += 64) {
        float v = mrow[n] ? rrow[n] : 0.0f;
        if (v == 0.0f) v = -1.0e6f;
        mx = fmaxf(mx, v);
    }
    for (int off = 32; off; off >>= 1) mx = fmaxf(mx, __shfl_xor(mx, off, 64));
    if (lane == 0) out[idx] = mx;
}

}  // namespace

extern "C" void kernel_launch(void* const* d_in, const int* in_sizes, int n_in,
                              void* d_out, int out_size, void* d_ws, size_t ws_size,
                              hipStream_t stream) {
    const float* nodes_glove  = (const float*)d_in[0];
    const float* query_glove  = (const float*)d_in[1];
    const float* adj          = (const float*)d_in[2];
    const int*   nodes_length = (const int*)d_in[3];
    const int*   maskp        = (const int*)d_in[4];
    const float* Wn = (const float*)d_in[5];
    const float* bn = (const float*)d_in[6];
    const float* Wq = (const float*)d_in[7];
    const float* bq = (const float*)d_in[8];
    const float* Wh = (const float*)d_in[9];
    const float* bh = (const float*)d_in[10];
    const float* Wc = (const float*)d_in[11];
    const float* bc = (const float*)d_in[12];
    const float* wa = (const float*)d_in[13];
    const float* W1 = (const float*)d_in[14];
    const float* b1 = (const float*)d_in[15];
    const float* W2 = (const float*)d_in[16];
    const float* b2 = (const float*)d_in[17];
    float* out = (float*)d_out;

    float* ws = (float*)d_ws;
    size_t off = 0;
    auto alloc = [&](size_t n) { float* p = ws + off; off += n; return p; };
    constexpr size_t ME  = (size_t)Bn * Nn * ENC;       // 2,048,000 fp32 elems
    constexpr size_t MEH = ME / 2;
    float* nc   = alloc(ME);
    float* Asum = alloc(ME);       // fp32 adjacency; then n2q; then part buf
    float* pa   = alloc(ME);       // fp32 partial att logits (lh @ Wc_lo)
    unsigned short* lh0 = (unsigned short*)alloc(MEH);
    unsigned short* lh1 = (unsigned short*)alloc(MEH);
    unsigned short* upd = (unsigned short*)alloc(MEH);
    unsigned short* hm  = (unsigned short*)alloc(MEH);
    unsigned short* gbf = (unsigned short*)alloc(ME * 2);   // [4000][2048] bf16
    float* qc   = alloc((size_t)Bn * Qn * ENC);
    float* rowmax = alloc(Bn * Nn);
    float* q2n    = alloc(Bn * ENC);
    float* raw    = alloc(Bn * Nn);
    unsigned short* WnT  = (unsigned short*)alloc((size_t)ENC * 320 / 2);
    unsigned short* WqT  = (unsigned short*)alloc((size_t)ENC * 320 / 2);
    unsigned short* WhcT = (unsigned short*)alloc((size_t)1024 * 512 / 2);
    unsigned short* WcHiT = (unsigned short*)alloc((size_t)512 * 512 / 2);
    unsigned short* W1T  = (unsigned short*)alloc((size_t)128 * 2048 / 2);
    alloc(16384);  // tail pad
    float* n2q  = Asum;            // phase 2
    float* part = Asum;            // phase 3 (after gbf consumed n2q)

    constexpr int M = Bn * Nn;  // 4000

    sum_adj_pad_k<<<dim3(Bn * Nn), 128, 0, stream>>>(adj, Asum);
    tcvt_all_k<<<dim3(16, 64, 6), 256, 0, stream>>>(Wn, Wq, Wh, Wc, W1,
                                                    WnT, WqT, WhcT, WcHiT, W1T);

    gemm_nc_k<<<dim3((M + 63) / 64, 8), 256, 0, stream>>>(nodes_glove, WnT, bn,
                                                          nodes_length, nc, lh0);
    gemm_qc_k<<<dim3((Bn * Qn + 63) / 64, 8), 256, 0, stream>>>(query_glove, WqT, bq, qc);

    // 3 hops; cur starts at lh0, after 3 swaps cur==lh1.
    unsigned short* cur = lh0;
    unsigned short* nxt = lh1;
    for (int h = 0; h < 3; ++h) {
        gemm_hmw_k<<<dim3((M + 63) / 64, 16), 256, 0, stream>>>(cur, WhcT, bh,
                                                                nodes_length, hm, pa);
        upd_sparse_k<<<dim3(M / 4), 256, 0, stream>>>(Asum, hm, upd);
        gemm_att_k<<<dim3((M + 63) / 64, 8), 256, 0, stream>>>(upd, cur, WcHiT, pa,
                                                               bc, nodes_length, nxt);
        unsigned short* tmp = cur; cur = nxt; nxt = tmp;
    }
    // cur == lh1 == final last_hop.

    sim_fused_k<<<dim3(Bn, 125), 256, 0, stream>>>(cur, qc, wa, n2q, rowmax);
    bvec_q2n_k<<<dim3(Bn), 512, 0, stream>>>(rowmax, nc, q2n);
    gbf_k<<<dim3(M), 256, 0, stream>>>(nc, n2q, q2n, gbf);       // consumes n2q
    gemm_final_k<<<dim3((M + 63) / 64, 2, 4), 256, 0, stream>>>(gbf, W1T, part);
    final_reduce_k<<<dim3((M + 3) / 4), 256, 0, stream>>>(part, b1, W2, b2, raw);
    predmax_k<<<dim3((Bn * NCn + 3) / 4), 256, 0, stream>>>(maskp, raw, out);
}

// Round 17
// 329.591 us; speedup vs baseline: 1.1139x; 1.0277x over previous
//
#include <hip/hip_runtime.h>
#include <hip/hip_bf16.h>
#include <math.h>
#include <stdint.h>

namespace {

constexpr int Bn  = 8;
constexpr int Nn  = 500;
constexpr int Qn  = 25;
constexpr int ENC = 512;
constexpr int DIN = 300;
constexpr int NCn = 70;
constexpr int NETn = 3;

typedef __attribute__((ext_vector_type(8))) short bf16x8_t;
typedef __attribute__((ext_vector_type(4))) float f32x4_t;

__device__ __forceinline__ unsigned short f2bf(float f) {
    union { __hip_bfloat16 b; unsigned short u; } r;
    r.b = __float2bfloat16(f);
    return r.u;
}
__device__ __forceinline__ bf16x8_t cvt8(float4 f0, float4 f1) {
    union { bf16x8_t v; __hip_bfloat162 b[4]; } r;
    r.b[0] = __float22bfloat162_rn(make_float2(f0.x, f0.y));
    r.b[1] = __float22bfloat162_rn(make_float2(f0.z, f0.w));
    r.b[2] = __float22bfloat162_rn(make_float2(f1.x, f1.y));
    r.b[3] = __float22bfloat162_rn(make_float2(f1.z, f1.w));
    return r.v;
}
__device__ __forceinline__ float bf2f(unsigned short h) {
    unsigned int u = ((unsigned int)h) << 16;
    return __builtin_bit_cast(float, u);
}
__device__ __forceinline__ float sigmoidf_(float x) { return 1.0f / (1.0f + expf(-x)); }

// ---------------------------------------------------------------------------
// Fused prep: z=1 -> Asum (2 adjacency rows per block); z=0 -> all weight
// transposes (tile decoded from blockIdx.x).  Block-uniform paths only.
// sel2: Wh -> WhcT rows 0..511.  sel3: Wc rows 512..1023 -> WhcT rows 512..1023
// (WhcT = B^T for lh @ [Wh | Wc_lo]).  sel4: Wc rows 0..511 -> WcHiT.
__global__ __launch_bounds__(256) void prep_k(
    const float* __restrict__ adj, float* __restrict__ Asum,
    const float* __restrict__ Wn, const float* __restrict__ Wq,
    const float* __restrict__ Wh, const float* __restrict__ Wc,
    const float* __restrict__ W1,
    unsigned short* __restrict__ WnT, unsigned short* __restrict__ WqT,
    unsigned short* __restrict__ WhcT, unsigned short* __restrict__ WcHiT,
    unsigned short* __restrict__ W1T) {
    if (blockIdx.z == 1) {
        // Asum[b][i][j] = sum_e adj[b,e,i,j], j padded 500->512 with zeros.
        int bi = blockIdx.x * 2 + (threadIdx.x >> 7);
        if (bi >= Bn * Nn) return;
        int b = bi / Nn, i = bi - b * Nn;
        int j = (threadIdx.x & 127) * 4;
        float4 s = make_float4(0.f, 0.f, 0.f, 0.f);
        if (j < Nn) {
#pragma unroll
            for (int e = 0; e < NETn; ++e) {
                const float* p = adj + (((size_t)(b * NETn + e) * Nn) + i) * Nn + j;
                float4 v = *(const float4*)p;
                s.x += v.x; s.y += v.y; s.z += v.z; s.w += v.w;
            }
        }
        *(float4*)(Asum + ((size_t)bi) * 512 + j) = s;
        return;
    }
    // z == 0: weight transpose tiles.
    __shared__ float tile[32][33];
    int x = blockIdx.x;
    const float* in; unsigned short* out; int K, N, Kpad, tx, ty;
    if (x < 160)       { in = Wn; out = WnT; K = DIN; N = ENC; Kpad = 320;
                         tx = x & 15; ty = x >> 4; }
    else if (x < 320)  { int l = x - 160; in = Wq; out = WqT; K = DIN; N = ENC;
                         Kpad = 320; tx = l & 15; ty = l >> 4; }
    else if (x < 576)  { int l = x - 320; in = Wh; out = WhcT; K = 512; N = ENC;
                         Kpad = 512; tx = l & 15; ty = l >> 4; }
    else if (x < 832)  { int l = x - 576; in = Wc + (size_t)512 * ENC;
                         out = WhcT + (size_t)512 * 512; K = 512; N = ENC;
                         Kpad = 512; tx = l & 15; ty = l >> 4; }
    else if (x < 1088) { int l = x - 832; in = Wc; out = WcHiT; K = 512; N = ENC;
                         Kpad = 512; tx = l & 15; ty = l >> 4; }
    else if (x < 1344) { int l = x - 1088; in = W1; out = W1T; K = 2048; N = 128;
                         Kpad = 2048; tx = l & 3; ty = l >> 2; }
    else return;
    int n0 = tx * 32, k0 = ty * 32;
    int ltx = threadIdx.x & 31, lty = threadIdx.x >> 5;
#pragma unroll
    for (int r = 0; r < 4; ++r) {
        int k = k0 + lty * 4 + r;
        int n = n0 + ltx;
        tile[lty * 4 + r][ltx] = (k < K && n < N) ? in[(size_t)k * N + n] : 0.0f;
    }
    __syncthreads();
#pragma unroll
    for (int r = 0; r < 4; ++r) {
        int n = n0 + lty * 4 + r;
        int k = k0 + ltx;
        if (n < N && k < Kpad) out[(size_t)n * Kpad + k] = f2bf(tile[ltx][lty * 4 + r]);
    }
}

// ---------------------------------------------------------------------------
// MFMA core, BK=64 (R13/R14/R16-proven): 64x64 tile, 4 waves, double-buffered
// LDS, one barrier per 64-k step.  AMODE 0: A fp32 (A2 concat, Klim clamp).
// AMODE 1: A bf16 (Abf; optional Abf2 concat).  Bt: bf16 B^T [n][k].
// NOTE (R15 lesson): keep LDS at 32KB/block -> 4 blocks/CU. The 128x64-tile
// variant (96KB LDS, 1 block/CU) REGRESSED 340->367us — blocks/CU dominates.
template <int AMODE>
__device__ __forceinline__ void mfma_core(
    const float* __restrict__ A, const float* __restrict__ A2,
    const unsigned short* __restrict__ Abf, const unsigned short* __restrict__ Abf2,
    int lda, int ksplit, int Klim,
    const unsigned short* __restrict__ Bt, int ldb,
    int m0, int n0, int K, int Mlim,
    unsigned short* As, unsigned short* Bts, f32x4_t acc[2][2]) {
    const int t = threadIdx.x;
    const int lane = t & 63;
    const int w = t >> 6;
    const int sm = t >> 2;
    const int sp = t & 3;
    const int sq = sp ^ ((sm >> 1) & 3);
    const int arow = m0 + sm;
    const bool rowok = arow < Mlim;
    const int wm = (w & 1) * 32, wn = (w >> 1) * 32;
    const int quad = lane >> 4, cidx = lane & 15;
    const int am0 = wm + cidx, am1 = wm + 16 + cidx;
    const int an0 = wn + cidx, an1 = wn + 16 + cidx;
    const int apo0 = am0 * 32 + (quad ^ ((am0 >> 1) & 3)) * 8;
    const int apo1 = am1 * 32 + (quad ^ ((am1 >> 1) & 3)) * 8;
    const int bpo0 = an0 * 32 + (quad ^ ((an0 >> 1) & 3)) * 8;
    const int bpo1 = an1 * 32 + (quad ^ ((an1 >> 1) & 3)) * 8;

    bf16x8_t ast0, ast1, bst0, bst1;
    auto stageA = [&](int kg) -> bf16x8_t {
        if (AMODE == 1) {
            bf16x8_t r = {0, 0, 0, 0, 0, 0, 0, 0};
            if (rowok) {
                const unsigned short* src =
                    (Abf2 != nullptr && kg >= ksplit)
                        ? Abf2 + (size_t)arow * lda + (kg - ksplit)
                        : Abf + (size_t)arow * lda + kg;
                r = *(const bf16x8_t*)src;
            }
            return r;
        } else {
            float4 f0 = make_float4(0.f, 0.f, 0.f, 0.f);
            float4 f1 = make_float4(0.f, 0.f, 0.f, 0.f);
            if (rowok) {
                const float* src = (A2 != nullptr && kg >= ksplit)
                                       ? A2 + (size_t)arow * lda + (kg - ksplit)
                                       : A + (size_t)arow * lda + kg;
                if (kg + 8 <= Klim) {
                    f0 = *(const float4*)src;
                    f1 = *(const float4*)(src + 4);
                } else if (kg + 4 <= Klim) {
                    f0 = *(const float4*)src;
                }
            }
            return cvt8(f0, f1);
        }
    };
    auto stage = [&](int k0) {
        int kg0 = k0 + sq * 8;
        int kg1 = k0 + 32 + sq * 8;
        ast0 = stageA(kg0);
        ast1 = stageA(kg1);
        const unsigned short* brow = Bt + (size_t)(n0 + sm) * ldb;
        bst0 = *(const bf16x8_t*)(brow + kg0);
        bst1 = *(const bf16x8_t*)(brow + kg1);
    };

    const int ktot = K >> 6;
    stage(0);
    *(bf16x8_t*)(As + t * 8) = ast0;
    *(bf16x8_t*)(As + 2048 + t * 8) = ast1;
    *(bf16x8_t*)(Bts + t * 8) = bst0;
    *(bf16x8_t*)(Bts + 2048 + t * 8) = bst1;
    for (int kt = 0; kt < ktot; ++kt) {
        __syncthreads();
        const int cur = (kt & 1) * 4096;
        const bool more = (kt + 1) < ktot;
        if (more) stage((kt + 1) << 6);
        {
            bf16x8_t a0 = *(const bf16x8_t*)(As + cur + apo0);
            bf16x8_t a1 = *(const bf16x8_t*)(As + cur + apo1);
            bf16x8_t b0 = *(const bf16x8_t*)(Bts + cur + bpo0);
            bf16x8_t b1 = *(const bf16x8_t*)(Bts + cur + bpo1);
            acc[0][0] = __builtin_amdgcn_mfma_f32_16x16x32_bf16(a0, b0, acc[0][0], 0, 0, 0);
            acc[0][1] = __builtin_amdgcn_mfma_f32_16x16x32_bf16(a0, b1, acc[0][1], 0, 0, 0);
            acc[1][0] = __builtin_amdgcn_mfma_f32_16x16x32_bf16(a1, b0, acc[1][0], 0, 0, 0);
            acc[1][1] = __builtin_amdgcn_mfma_f32_16x16x32_bf16(a1, b1, acc[1][1], 0, 0, 0);
        }
        {
            bf16x8_t a0 = *(const bf16x8_t*)(As + cur + 2048 + apo0);
            bf16x8_t a1 = *(const bf16x8_t*)(As + cur + 2048 + apo1);
            bf16x8_t b0 = *(const bf16x8_t*)(Bts + cur + 2048 + bpo0);
            bf16x8_t b1 = *(const bf16x8_t*)(Bts + cur + 2048 + bpo1);
            acc[0][0] = __builtin_amdgcn_mfma_f32_16x16x32_bf16(a0, b0, acc[0][0], 0, 0, 0);
            acc[0][1] = __builtin_amdgcn_mfma_f32_16x16x32_bf16(a0, b1, acc[0][1], 0, 0, 0);
            acc[1][0] = __builtin_amdgcn_mfma_f32_16x16x32_bf16(a1, b0, acc[1][0], 0, 0, 0);
            acc[1][1] = __builtin_amdgcn_mfma_f32_16x16x32_bf16(a1, b1, acc[1][1], 0, 0, 0);
        }
        if (more) {
            const int nxt = ((kt + 1) & 1) * 4096;
            *(bf16x8_t*)(As + nxt + t * 8) = ast0;
            *(bf16x8_t*)(As + nxt + 2048 + t * 8) = ast1;
            *(bf16x8_t*)(Bts + nxt + t * 8) = bst0;
            *(bf16x8_t*)(Bts + nxt + 2048 + t * 8) = bst1;
        }
    }
}

#define EPI_SETUP                                         \
    int t = threadIdx.x, lane = t & 63, w = t >> 6;       \
    int wm = (w & 1) * 32, wn = (w >> 1) * 32;            \
    int quad = lane >> 4, cidx = lane & 15;               \
    (void)wm; (void)wn; (void)quad; (void)cidx;

// ---------------------------------------------------------------------------
// Fused input GEMMs, grid (67, 8):
//   x <  63: nc = tanh(ng@Wn+bn) fp32; lh0 = bf16(nc * rowmask)
//   x >= 63: qc = qg@Wq + bq
__global__ __launch_bounds__(256) void gemm_in_k(const float* __restrict__ ng,
                                                 const float* __restrict__ qg,
                                                 const unsigned short* __restrict__ WnT,
                                                 const unsigned short* __restrict__ WqT,
                                                 const float* __restrict__ bn,
                                                 const float* __restrict__ bq,
                                                 const int* __restrict__ lens,
                                                 float* __restrict__ nc,
                                                 unsigned short* __restrict__ lh0,
                                                 float* __restrict__ qc) {
    __shared__ __align__(16) unsigned short As[8192], Bts[8192];
    f32x4_t z = {0.f, 0.f, 0.f, 0.f};
    f32x4_t acc[2][2] = {{z, z}, {z, z}};
    const bool isq = blockIdx.x >= 63;
    int m0 = (isq ? (blockIdx.x - 63) : blockIdx.x) * 64;
    int n0 = blockIdx.y * 64;
    const float* A = isq ? qg : ng;
    const unsigned short* Bt = isq ? WqT : WnT;
    const int Mlim = isq ? Bn * Qn : Bn * Nn;
    mfma_core<0>(A, nullptr, nullptr, nullptr, DIN, 1 << 30, DIN, Bt, 320,
                 m0, n0, 320, Mlim, As, Bts, acc);
    EPI_SETUP
#pragma unroll
    for (int nj = 0; nj < 2; ++nj) {
        int col = n0 + wn + nj * 16 + cidx;
        float bias = isq ? bq[col] : bn[col];
#pragma unroll
        for (int mi = 0; mi < 2; ++mi) {
#pragma unroll
            for (int r = 0; r < 4; ++r) {
                int row = m0 + wm + mi * 16 + quad * 4 + r;
                if (row < Mlim) {
                    float v = acc[mi][nj][r] + bias;
                    if (isq) {
                        qc[(size_t)row * ENC + col] = v;
                    } else {
                        float tv = tanhf(v);
                        int b = row / Nn, i = row - b * Nn;
                        float rm = (i < lens[b]) ? 1.0f : 0.0f;
                        nc[(size_t)row * ENC + col] = tv;
                        lh0[(size_t)row * ENC + col] = f2bf(tv * rm);
                    }
                }
            }
        }
    }
}

// ---------------------------------------------------------------------------
// Wide hop GEMM: lh @ [Wh | Wc_lo]  (N=1024, K=512).
// cols 0..511  -> hm = bf16((x + bh)*rm)
// cols 512..1023 -> pa = x  (fp32 partial att logits, lh @ Wc_lo)
__global__ __launch_bounds__(256) void gemm_hmw_k(const unsigned short* __restrict__ lh,
                                                  const unsigned short* __restrict__ WhcT,
                                                  const float* __restrict__ bh,
                                                  const int* __restrict__ lens,
                                                  unsigned short* __restrict__ hm,
                                                  float* __restrict__ pa) {
    __shared__ __align__(16) unsigned short As[8192], Bts[8192];
    f32x4_t z = {0.f, 0.f, 0.f, 0.f};
    f32x4_t acc[2][2] = {{z, z}, {z, z}};
    int m0 = blockIdx.x * 64, n0 = blockIdx.y * 64;   // n0 in [0,1024)
    mfma_core<1>(nullptr, nullptr, lh, nullptr, ENC, 1 << 30, ENC, WhcT, 512,
                 m0, n0, ENC, Bn * Nn, As, Bts, acc);
    EPI_SETUP
#pragma unroll
    for (int nj = 0; nj < 2; ++nj) {
        int col = n0 + wn + nj * 16 + cidx;
        bool ishm = col < 512;
        float bias = ishm ? bh[col] : 0.0f;
#pragma unroll
        for (int mi = 0; mi < 2; ++mi) {
#pragma unroll
            for (int r = 0; r < 4; ++r) {
                int row = m0 + wm + mi * 16 + quad * 4 + r;
                if (row < Bn * Nn) {
                    int b = row / Nn, i = row - b * Nn;
                    float rm = (i < lens[b]) ? 1.0f : 0.0f;
                    float v = acc[mi][nj][r];
                    if (ishm) {
                        hm[(size_t)row * ENC + col] = f2bf((v + bias) * rm);
                    } else {
                        pa[(size_t)row * ENC + (col - 512)] = v;
                    }
                }
            }
        }
    }
}

// ---------------------------------------------------------------------------
// Sparse aggregation: upd[b,i,:] = hm[b,i,:] + sum_j Asum[b,i,j]*hm[b,j,:].
__global__ __launch_bounds__(256) void upd_sparse_k(const float* __restrict__ Asum,
                                                    const unsigned short* __restrict__ hm,
                                                    unsigned short* __restrict__ upd) {
    int wv = threadIdx.x >> 6, lane = threadIdx.x & 63;
    int row = blockIdx.x * 4 + wv;
    int b = row / Nn, i = row - b * Nn;
    const float* arow = Asum + (size_t)row * 512;
    const unsigned short* hmb = hm + (size_t)b * Nn * ENC;
    int d0 = lane * 8;

    float acc[8];
    {
        bf16x8_t h = *(const bf16x8_t*)(hmb + (size_t)i * ENC + d0);
#pragma unroll
        for (int j = 0; j < 8; ++j) acc[j] = bf2f((unsigned short)h[j]);
    }
#pragma unroll
    for (int c = 0; c < 8; ++c) {
        int j = c * 64 + lane;
        float val = (j < Nn) ? arow[j] : 0.0f;
        unsigned long long mask = __ballot(val != 0.0f);
        while (mask) {
            int b0 = __ffsll((unsigned long long)mask) - 1;
            mask &= mask - 1;
            int b1 = -1;
            if (mask) { b1 = __ffsll((unsigned long long)mask) - 1; mask &= mask - 1; }
            float v0 = __shfl(val, b0, 64);
            bf16x8_t x = *(const bf16x8_t*)(hmb + (size_t)(c * 64 + b0) * ENC + d0);
            float v1 = 0.0f;
            bf16x8_t y = {0, 0, 0, 0, 0, 0, 0, 0};
            if (b1 >= 0) {
                v1 = __shfl(val, b1, 64);
                y = *(const bf16x8_t*)(hmb + (size_t)(c * 64 + b1) * ENC + d0);
            }
#pragma unroll
            for (int k = 0; k < 8; ++k)
                acc[k] += v0 * bf2f((unsigned short)x[k]) + v1 * bf2f((unsigned short)y[k]);
        }
    }
    float4 o0 = make_float4(acc[0], acc[1], acc[2], acc[3]);
    float4 o1 = make_float4(acc[4], acc[5], acc[6], acc[7]);
    *(bf16x8_t*)(upd + (size_t)row * ENC + d0) = cvt8(o0, o1);
}

// ---------------------------------------------------------------------------
// att = sigmoid(upd@Wc_hi + pa + bc)*rm; lh_out = bf16(att*tanh(upd)+(1-att)*lh)
__global__ __launch_bounds__(256) void gemm_att_k(const unsigned short* __restrict__ upd,
                                                  const unsigned short* __restrict__ lh,
                                                  const unsigned short* __restrict__ WcHiT,
                                                  const float* __restrict__ pa,
                                                  const float* __restrict__ bc,
                                                  const int* __restrict__ lens,
                                                  unsigned short* __restrict__ lh_out) {
    __shared__ __align__(16) unsigned short As[8192], Bts[8192];
    f32x4_t z = {0.f, 0.f, 0.f, 0.f};
    f32x4_t acc[2][2] = {{z, z}, {z, z}};
    int m0 = blockIdx.x * 64, n0 = blockIdx.y * 64;
    mfma_core<1>(nullptr, nullptr, upd, nullptr, ENC, 1 << 30, ENC, WcHiT, 512,
                 m0, n0, ENC, Bn * Nn, As, Bts, acc);
    EPI_SETUP
#pragma unroll
    for (int nj = 0; nj < 2; ++nj) {
        int col = n0 + wn + nj * 16 + cidx;
        float bias = bc[col];
#pragma unroll
        for (int mi = 0; mi < 2; ++mi) {
#pragma unroll
            for (int r = 0; r < 4; ++r) {
                int row = m0 + wm + mi * 16 + quad * 4 + r;
                if (row < Bn * Nn) {
                    int b = row / Nn, i = row - b * Nn;
                    float rm = (i < lens[b]) ? 1.0f : 0.0f;
                    size_t off = (size_t)row * ENC + col;
                    float a = sigmoidf_(acc[mi][nj][r] + pa[off] + bias) * rm;
                    float u = bf2f(upd[off]);
                    float l = bf2f(lh[off]);
                    lh_out[off] = f2bf(a * tanhf(u) + (1.0f - a) * l);
                }
            }
        }
    }
}

// ---------------------------------------------------------------------------
// Materialize g = [nc | n2q | nc*n2q | nc*q2n] as bf16 [4000][2048].
__global__ __launch_bounds__(256) void gbf_k(const float* __restrict__ nc,
                                             const float* __restrict__ n2q,
                                             const float* __restrict__ q2n,
                                             unsigned short* __restrict__ gbf) {
    int row = blockIdx.x;
    int b = row / Nn;
    int t = threadIdx.x;
    int seg = t >> 6;
    int d = (t & 63) * 8;
    size_t off = (size_t)row * ENC + d;
    float4 a0, a1;
    if (seg == 0) {
        a0 = *(const float4*)(nc + off); a1 = *(const float4*)(nc + off + 4);
    } else if (seg == 1) {
        a0 = *(const float4*)(n2q + off); a1 = *(const float4*)(n2q + off + 4);
    } else if (seg == 2) {
        float4 x0 = *(const float4*)(nc + off), x1 = *(const float4*)(nc + off + 4);
        float4 y0 = *(const float4*)(n2q + off), y1 = *(const float4*)(n2q + off + 4);
        a0 = make_float4(x0.x * y0.x, x0.y * y0.y, x0.z * y0.z, x0.w * y0.w);
        a1 = make_float4(x1.x * y1.x, x1.y * y1.y, x1.z * y1.z, x1.w * y1.w);
    } else {
        float4 x0 = *(const float4*)(nc + off), x1 = *(const float4*)(nc + off + 4);
        const float* qp = q2n + (size_t)b * ENC + d;
        float4 y0 = *(const float4*)qp, y1 = *(const float4*)(qp + 4);
        a0 = make_float4(x0.x * y0.x, x0.y * y0.y, x0.z * y0.z, x0.w * y0.w);
        a1 = make_float4(x1.x * y1.x, x1.y * y1.y, x1.z * y1.z, x1.w * y1.w);
    }
    *(bf16x8_t*)(gbf + (size_t)row * 2048 + seg * 512 + d) = cvt8(a0, a1);
}

// ---------------------------------------------------------------------------
// g @ W1 split-K partials via MFMA; z = K-slice in [0,4) (512 wide).
__global__ __launch_bounds__(256) void gemm_final_k(const unsigned short* __restrict__ gbf,
                                                    const unsigned short* __restrict__ W1T,
                                                    float* __restrict__ part) {
    __shared__ __align__(16) unsigned short As[8192], Bts[8192];
    f32x4_t z4 = {0.f, 0.f, 0.f, 0.f};
    f32x4_t acc[2][2] = {{z4, z4}, {z4, z4}};
    int zz = blockIdx.z;
    int m0 = blockIdx.x * 64, n0 = blockIdx.y * 64;
    mfma_core<1>(nullptr, nullptr, gbf + zz * 512, nullptr, 2048, 1 << 30, 1 << 30,
                 W1T + zz * 512, 2048, m0, n0, 512, Bn * Nn, As, Bts, acc);
    EPI_SETUP
    constexpr int M = Bn * Nn;
#pragma unroll
    for (int nj = 0; nj < 2; ++nj) {
        int col = n0 + wn + nj * 16 + cidx;
#pragma unroll
        for (int mi = 0; mi < 2; ++mi) {
#pragma unroll
            for (int r = 0; r < 4; ++r) {
                int row = m0 + wm + mi * 16 + quad * 4 + r;
                if (row < M) part[((size_t)zz * M + row) * 128 + col] = acc[mi][nj][r];
            }
        }
    }
}

// ---------------------------------------------------------------------------
// Fused sim -> softmax(q) -> nodes2query + rowmax.  One wave per n-row.
__global__ __launch_bounds__(256) void sim_fused_k(const unsigned short* __restrict__ lh,
                                                   const float* __restrict__ qc,
                                                   const float* __restrict__ wa,
                                                   float* __restrict__ n2q,
                                                   float* __restrict__ rowmax) {
    __shared__ float qcs[Qn * ENC];
    __shared__ float qdot[32];
    int b = blockIdx.x;
    int t = threadIdx.x;
    const float* qcb = qc + (size_t)b * Qn * ENC;
    for (int i = t * 4; i < Qn * ENC; i += 1024) *(float4*)&qcs[i] = *(const float4*)&qcb[i];
    __syncthreads();
    {
        int q = t >> 3, j = t & 7;
        if (q < Qn) {
            float s = 0.f;
            for (int k = 0; k < 64; ++k) {
                int d = j + 8 * k;
                s += qcs[q * ENC + d] * wa[ENC + d];
            }
            s += __shfl_xor(s, 1, 64);
            s += __shfl_xor(s, 2, 64);
            s += __shfl_xor(s, 4, 64);
            if (j == 0) qdot[q] = s;
        }
    }
    __syncthreads();

    int wv = t >> 6, lane = t & 63;
    int n = blockIdx.y * 4 + wv;
    int dA = lane * 4;
    int dB = 256 + lane * 4;
    const unsigned short* lrow = lh + ((size_t)b * Nn + n) * ENC;
    ushort4 ua = *(const ushort4*)(lrow + dA);
    ushort4 ub = *(const ushort4*)(lrow + dB);
    float lv[8] = {bf2f(ua.x), bf2f(ua.y), bf2f(ua.z), bf2f(ua.w),
                   bf2f(ub.x), bf2f(ub.y), bf2f(ub.z), bf2f(ub.w)};
    float ndp = 0.f;
    float lvs[8];
#pragma unroll
    for (int j = 0; j < 4; ++j) {
        ndp += lv[j] * wa[dA + j];
        lvs[j] = lv[j] * wa[2 * ENC + dA + j];
        ndp += lv[4 + j] * wa[dB + j];
        lvs[4 + j] = lv[4 + j] * wa[2 * ENC + dB + j];
    }
#pragma unroll
    for (int off = 32; off; off >>= 1) ndp += __shfl_xor(ndp, off, 64);

    float s_[Qn];
#pragma unroll
    for (int q = 0; q < Qn; ++q) {
        float4 qa = *(const float4*)(qcs + q * ENC + dA);
        float4 qb = *(const float4*)(qcs + q * ENC + dB);
        s_[q] = lvs[0] * qa.x + lvs[1] * qa.y + lvs[2] * qa.z + lvs[3] * qa.w +
                lvs[4] * qb.x + lvs[5] * qb.y + lvs[6] * qb.z + lvs[7] * qb.w;
    }
#pragma unroll
    for (int q = 0; q < Qn; ++q) {
#pragma unroll
        for (int off = 32; off; off >>= 1) s_[q] += __shfl_xor(s_[q], off, 64);
    }
    float mx = -INFINITY;
#pragma unroll
    for (int q = 0; q < Qn; ++q) {
        s_[q] += ndp + qdot[q];
        mx = fmaxf(mx, s_[q]);
    }
    float sum = 0.f;
#pragma unroll
    for (int q = 0; q < Qn; ++q) { s_[q] = expf(s_[q] - mx); sum += s_[q]; }
    float inv = 1.0f / sum;
    float o[8] = {};
#pragma unroll
    for (int q = 0; q < Qn; ++q) {
        float4 qa = *(const float4*)(qcs + q * ENC + dA);
        float4 qb = *(const float4*)(qcs + q * ENC + dB);
        float p = s_[q] * inv;
        o[0] += p * qa.x; o[1] += p * qa.y; o[2] += p * qa.z; o[3] += p * qa.w;
        o[4] += p * qb.x; o[5] += p * qb.y; o[6] += p * qb.z; o[7] += p * qb.w;
    }
    float* orow = n2q + ((size_t)b * Nn + n) * ENC;
    *(float4*)(orow + dA) = make_float4(o[0], o[1], o[2], o[3]);
    *(float4*)(orow + dB) = make_float4(o[4], o[5], o[6], o[7]);
    if (lane == 0) rowmax[b * Nn + n] = mx;
}

// ---------------------------------------------------------------------------
// Fused bvec (softmax over rowmax) + q2n (bvec-weighted sum of nc).
__global__ __launch_bounds__(512) void bvec_q2n_k(const float* __restrict__ rowmax,
                                                  const float* __restrict__ nc,
                                                  float* __restrict__ q2n) {
    __shared__ float red[8];
    __shared__ float bvs[512];
    int b = blockIdx.x, t = threadIdx.x;
    float v = (t < Nn) ? rowmax[b * Nn + t] : -INFINITY;
    float m = v;
    for (int off = 32; off; off >>= 1) m = fmaxf(m, __shfl_xor(m, off, 64));
    if ((t & 63) == 0) red[t >> 6] = m;
    __syncthreads();
    float bm = red[0];
    for (int i = 1; i < 8; ++i) bm = fmaxf(bm, red[i]);
    float e = (t < Nn) ? expf(v - bm) : 0.0f;
    float ssum = e;
    for (int off = 32; off; off >>= 1) ssum += __shfl_xor(ssum, off, 64);
    __syncthreads();
    if ((t & 63) == 0) red[t >> 6] = ssum;
    __syncthreads();
    float tot = 0.f;
    for (int i = 0; i < 8; ++i) tot += red[i];
    bvs[t] = e / tot;
    __syncthreads();
    const float* ncb = nc + (size_t)b * Nn * ENC;
    float acc = 0.f;
    for (int n = 0; n < Nn; ++n) acc = fmaf(bvs[n], ncb[(size_t)n * ENC + t], acc);
    q2n[b * ENC + t] = acc;
}

// ---------------------------------------------------------------------------
// raw[row] = b2 + sum_h tanh(sum_z part[z][row][h] + b1[h]) * W2[h]
__global__ __launch_bounds__(256) void final_reduce_k(const float* __restrict__ part,
                                                      const float* __restrict__ b1p,
                                                      const float* __restrict__ W2p,
                                                      const float* __restrict__ b2p,
                                                      float* __restrict__ raw) {
    constexpr int M = Bn * Nn;
    int wave = threadIdx.x >> 6, lane = threadIdx.x & 63;
    int row = blockIdx.x * 4 + wave;
    if (row >= M) return;
    float v0 = 0.f, v1 = 0.f;
#pragma unroll
    for (int s = 0; s < 4; ++s) {
        const float* pr = part + ((size_t)s * M + row) * 128;
        v0 += pr[lane];
        v1 += pr[lane + 64];
    }
    float p = tanhf(v0 + b1p[lane]) * W2p[lane] + tanhf(v1 + b1p[lane + 64]) * W2p[lane + 64];
    for (int off = 32; off; off >>= 1) p += __shfl_xor(p, off, 64);
    if (lane == 0) raw[row] = p + b2p[0];
}

// ---------------------------------------------------------------------------
__global__ __launch_bounds__(256) void predmax_k(const int* __restrict__ mask,
                                                 const float* __restrict__ raw,
                                                 float* __restrict__ out) {
    int idx = blockIdx.x * 4 + (threadIdx.x >> 6);
    int lane = threadIdx.x & 63;
    if (idx >= Bn * NCn) return;
    int b = idx / NCn, c = idx - b * NCn;
    const int* mrow = mask + ((size_t)b * NCn + c) * Nn;
    const float* rrow = raw + (size_t)b * Nn;
    float mx = -INFINITY;
    for (int n = lane; n < Nn; n += 64) {
        float v = mrow[n] ? rrow[n] : 0.0f;
        if (v == 0.0f) v = -1.0e6f;
        mx = fmaxf(mx, v);
    }
    for (int off = 32; off; off >>= 1) mx = fmaxf(mx, __shfl_xor(mx, off, 64));
    if (lane == 0) out[idx] = mx;
}

}  // namespace

extern "C" void kernel_launch(void* const* d_in, const int* in_sizes, int n_in,
                              void* d_out, int out_size, void* d_ws, size_t ws_size,
                              hipStream_t stream) {
    const float* nodes_glove  = (const float*)d_in[0];
    const float* query_glove  = (const float*)d_in[1];
    const float* adj          = (const float*)d_in[2];
    const int*   nodes_length = (const int*)d_in[3];
    const int*   maskp        = (const int*)d_in[4];
    const float* Wn = (const float*)d_in[5];
    const float* bn = (const float*)d_in[6];
    const float* Wq = (const float*)d_in[7];
    const float* bq = (const float*)d_in[8];
    const float* Wh = (const float*)d_in[9];
    const float* bh = (const float*)d_in[10];
    const float* Wc = (const float*)d_in[11];
    const float* bc = (const float*)d_in[12];
    const float* wa = (const float*)d_in[13];
    const float* W1 = (const float*)d_in[14];
    const float* b1 = (const float*)d_in[15];
    const float* W2 = (const float*)d_in[16];
    const float* b2 = (const float*)d_in[17];
    float* out = (float*)d_out;

    float* ws = (float*)d_ws;
    size_t off = 0;
    auto alloc = [&](size_t n) { float* p = ws + off; off += n; return p; };
    constexpr size_t ME  = (size_t)Bn * Nn * ENC;       // 2,048,000 fp32 elems
    constexpr size_t MEH = ME / 2;
    float* nc   = alloc(ME);
    float* Asum = alloc(ME);       // fp32 adjacency; then n2q; then part buf
    float* pa   = alloc(ME);       // fp32 partial att logits (lh @ Wc_lo)
    unsigned short* lh0 = (unsigned short*)alloc(MEH);
    unsigned short* lh1 = (unsigned short*)alloc(MEH);
    unsigned short* upd = (unsigned short*)alloc(MEH);
    unsigned short* hm  = (unsigned short*)alloc(MEH);
    unsigned short* gbf = (unsigned short*)alloc(ME * 2);   // [4000][2048] bf16
    float* qc   = alloc((size_t)Bn * Qn * ENC);
    float* rowmax = alloc(Bn * Nn);
    float* q2n    = alloc(Bn * ENC);
    float* raw    = alloc(Bn * Nn);
    unsigned short* WnT  = (unsigned short*)alloc((size_t)ENC * 320 / 2);
    unsigned short* WqT  = (unsigned short*)alloc((size_t)ENC * 320 / 2);
    unsigned short* WhcT = (unsigned short*)alloc((size_t)1024 * 512 / 2);
    unsigned short* WcHiT = (unsigned short*)alloc((size_t)512 * 512 / 2);
    unsigned short* W1T  = (unsigned short*)alloc((size_t)128 * 2048 / 2);
    alloc(16384);  // tail pad
    float* n2q  = Asum;            // phase 2
    float* part = Asum;            // phase 3 (after gbf consumed n2q)

    constexpr int M = Bn * Nn;  // 4000

    // Fused prep: adjacency sum (z=1) + all weight transposes (z=0).
    prep_k<<<dim3(2048, 1, 2), 256, 0, stream>>>(adj, Asum, Wn, Wq, Wh, Wc, W1,
                                                 WnT, WqT, WhcT, WcHiT, W1T);

    // Fused input GEMMs (nc: x<63, qc: x>=63).
    gemm_in_k<<<dim3(67, 8), 256, 0, stream>>>(nodes_glove, query_glove, WnT, WqT,
                                               bn, bq, nodes_length, nc, lh0, qc);

    // 3 hops; cur starts at lh0, after 3 swaps cur==lh1.
    unsigned short* cur = lh0;
    unsigned short* nxt = lh1;
    for (int h = 0; h < 3; ++h) {
        gemm_hmw_k<<<dim3((M + 63) / 64, 16), 256, 0, stream>>>(cur, WhcT, bh,
                                                                nodes_length, hm, pa);
        upd_sparse_k<<<dim3(M / 4), 256, 0, stream>>>(Asum, hm, upd);
        gemm_att_k<<<dim3((M + 63) / 64, 8), 256, 0, stream>>>(upd, cur, WcHiT, pa,
                                                               bc, nodes_length, nxt);
        unsigned short* tmp = cur; cur = nxt; nxt = tmp;
    }
    // cur == lh1 == final last_hop.

    sim_fused_k<<<dim3(Bn, 125), 256, 0, stream>>>(cur, qc, wa, n2q, rowmax);
    bvec_q2n_k<<<dim3(Bn), 512, 0, stream>>>(rowmax, nc, q2n);
    gbf_k<<<dim3(M), 256, 0, stream>>>(nc, n2q, q2n, gbf);       // consumes n2q
    gemm_final_k<<<dim3((M + 63) / 64, 2, 4), 256, 0, stream>>>(gbf, W1T, part);
    final_reduce_k<<<dim3((M + 3) / 4), 256, 0, stream>>>(part, b1, W2, b2, raw);
    predmax_k<<<dim3((Bn * NCn + 3) / 4), 256, 0, stream>>>(maskp, raw, out);
}